// Round 2
// baseline (7162.186 us; speedup 1.0000x reference)
//
#include <hip/hip_runtime.h>

// Net_32323923870241: graph fusion block, MI355X (gfx950)
// Reformulation: per-scale scatter-add of (feat[v] @ W.T) == (scatter-add of feat[v]) @ W.T
// -> CSR-ordered aggregation (no atomics) + one K=1920 bf16 MFMA GEMM per iteration.
// Round 2: workspace-adaptive chunking (round-1 crash = d_ws overflow), bf16 temp.

#define NN 250000
#define DD 128
#define EE 500000
#define ELE 50000
#define NITER 4
#define NL 14
#define M14 (NL*NN)              // 3,500,000 histogram entries
#define TOTE (12*EE + 2*ELE)     // 6,100,000 edges
#define SCHUNK 2048
#define NB1 ((M14 + SCHUNK - 1)/SCHUNK)   // 1709
#define KBIG (15*DD)             // 1920
#define BK 64
#define TILES_TOTAL ((NN + 127)/128)      // 1954

typedef unsigned short u16;
typedef __attribute__((ext_vector_type(4))) float f32x4;
typedef __attribute__((ext_vector_type(8))) __bf16 bf16x8;

static __device__ __forceinline__ unsigned f2bf(float f) {
  unsigned u = __float_as_uint(f);
  return (u + 0x7fffu + ((u >> 16) & 1u)) >> 16;   // RNE
}
static __device__ __forceinline__ float bflo(unsigned w){ return __uint_as_float(w << 16); }
static __device__ __forceinline__ float bfhi(unsigned w){ return __uint_as_float(w & 0xffff0000u); }

static __device__ __forceinline__ void gload16(const u16* g, u16* l) {
  __builtin_amdgcn_global_load_lds(
      (const __attribute__((address_space(1))) void*)g,
      (__attribute__((address_space(3))) void*)l, 16, 0, 0);
}

// ---------------- CSR build ----------------
__global__ void k_hist(const int* __restrict__ pu, const int* __restrict__ su,
                       const int* __restrict__ lu, const int* __restrict__ ru,
                       int* __restrict__ cnt) {
  int idx = blockIdx.x*256 + threadIdx.x;
  if (idx >= TOTE) return;
  int l, u;
  if (idx < 12*EE) {
    l = idx / EE; int e = idx - l*EE;
    u = (l < 6) ? pu[l*EE + e] : su[(l-6)*EE + e];
  } else {
    int r = idx - 12*EE;
    if (r < ELE) { l = 12; u = lu[r]; }
    else         { l = 13; u = ru[r - ELE]; }
  }
  atomicAdd(&cnt[l*NN + u], 1);
}

__global__ void k_scanA(const int* __restrict__ in, int* __restrict__ out, int* __restrict__ bsums) {
  __shared__ int lds[256];
  int t = threadIdx.x;
  int base = blockIdx.x*SCHUNK + t*8;
  int v[8]; int s = 0;
  #pragma unroll
  for (int j=0;j<8;j++){ int x = (base+j < M14) ? in[base+j] : 0; v[j] = s; s += x; }
  lds[t] = s; __syncthreads();
  for (int d=1; d<256; d<<=1) {
    int add = (t>=d) ? lds[t-d] : 0; __syncthreads();
    lds[t] += add; __syncthreads();
  }
  int incl = lds[t];
  int excl = incl - s;
  if (t == 255) bsums[blockIdx.x] = incl;
  #pragma unroll
  for (int j=0;j<8;j++) if (base+j < M14) out[base+j] = excl + v[j];
}

__global__ void k_scanB(int* __restrict__ data, int n) {
  __shared__ int lds[256];
  __shared__ int carry;
  int t = threadIdx.x;
  if (t == 0) carry = 0;
  __syncthreads();
  for (int base=0; base<n; base+=256) {
    int i = base + t;
    int x = (i < n) ? data[i] : 0;
    lds[t] = x; __syncthreads();
    for (int d=1; d<256; d<<=1) {
      int add = (t>=d) ? lds[t-d] : 0; __syncthreads();
      lds[t] += add; __syncthreads();
    }
    int incl = lds[t];
    int c = carry;
    if (i < n) data[i] = c + incl - x;
    __syncthreads();
    if (t == 255) carry = c + incl;
    __syncthreads();
  }
}

__global__ void k_scanC(int* __restrict__ out, const int* __restrict__ bsums) {
  int t = threadIdx.x;
  int base = blockIdx.x*SCHUNK + t*8;
  int add = bsums[blockIdx.x];
  #pragma unroll
  for (int j=0;j<8;j++) if (base+j < M14) out[base+j] += add;
  if (blockIdx.x == 0 && t == 0) out[M14] = TOTE;
}

__global__ void k_fill(const int* __restrict__ pu, const int* __restrict__ pv,
                       const int* __restrict__ su, const int* __restrict__ sv,
                       const int* __restrict__ lu, const int* __restrict__ lv,
                       const int* __restrict__ ru, const int* __restrict__ rv,
                       int* __restrict__ cursor, int* __restrict__ edge_v) {
  int idx = blockIdx.x*256 + threadIdx.x;
  if (idx >= TOTE) return;
  int l, u, v;
  if (idx < 12*EE) {
    l = idx / EE; int e = idx - l*EE;
    if (l < 6) { u = pu[l*EE+e]; v = pv[l*EE+e]; }
    else       { u = su[(l-6)*EE+e]; v = sv[(l-6)*EE+e]; }
  } else {
    int r = idx - 12*EE;
    if (r < ELE) { l = 12; u = lu[r]; v = lv[r]; }
    else         { l = 13; u = ru[r-ELE]; v = rv[r-ELE]; }
  }
  int pos = atomicAdd(&cursor[l*NN + u], 1);
  edge_v[pos] = v;
}

// ---------------- per-iteration kernels ----------------
__global__ void k_f2bf(const float* __restrict__ in, unsigned* __restrict__ out) {
  int i = blockIdx.x*256 + threadIdx.x;   // grid sized exactly NN*64
  float2 v = ((const float2*)in)[i];
  out[i] = f2bf(v.x) | (f2bf(v.y) << 16);
}

__global__ void k_bw(const float* __restrict__ Wc, const float* __restrict__ Wp,
                     const float* __restrict__ Ws, const float* __restrict__ Wl,
                     const float* __restrict__ Wr, const float* __restrict__ Wc2,
                     int it, u16* __restrict__ wcat, u16* __restrict__ wc2) {
  int i = blockIdx.x*256 + threadIdx.x;
  if (i < 128*KBIG) {
    int r = i / KBIG, K = i - r*KBIG;
    int s = K >> 7, c = K & 127;
    float val;
    if (s == 0)       val = Wc[(it*128 + r)*128 + c];
    else if (s <= 6)  val = Wp[((it*6 + (s-1))*128 + r)*128 + c];
    else if (s <= 12) val = Ws[((it*6 + (s-7))*128 + r)*128 + c];
    else if (s == 13) val = Wl[(it*128 + r)*128 + c];
    else              val = Wr[(it*128 + r)*128 + c];
    wcat[i] = (u16)f2bf(val);
  } else {
    int j = i - 128*KBIG;  // < 16384
    wc2[j] = (u16)f2bf(Wc2[it*16384 + j]);
  }
}

// slot 0: copy feat row; slots 1..14: CSR aggregation of list s-1
__global__ __launch_bounds__(256) void k_agg(const unsigned* __restrict__ featbf,
    const int* __restrict__ rowptr, const int* __restrict__ edge_v,
    unsigned* __restrict__ X, int chunk_base) {
  int wid = threadIdx.x >> 6, lane = threadIdx.x & 63;
  int nl = blockIdx.x*4 + wid;
  int s = blockIdx.y;
  int node = chunk_base + nl;
  unsigned out = 0;
  if (s == 0) {
    if (node < NN) out = featbf[(size_t)node*64 + lane];
  } else if (node < NN) {
    float ax = 0.f, ay = 0.f;
    int idx = (s-1)*NN + node;
    int st = rowptr[idx], en = rowptr[idx+1];
    for (int e=st; e<en; e++) {
      int v = edge_v[e];
      unsigned w = featbf[(size_t)v*64 + lane];
      ax += bflo(w); ay += bfhi(w);
    }
    out = f2bf(ax) | (f2bf(ay) << 16);
  }
  X[(size_t)nl*(KBIG/2) + s*64 + lane] = out;
}

// C[row][col] = sum_K A[row][K] * B[col][K]; output converted to bf16 (u16).
__global__ __launch_bounds__(256) void gemm_bt(
    const u16* __restrict__ A, int lda,
    const u16* __restrict__ B, int ldb,
    u16* __restrict__ Cbf, int K, int row0_abs) {
  __shared__ u16 As[128*BK];
  __shared__ u16 Bs[128*BK];
  int tid = threadIdx.x, wid = tid >> 6, lane = tid & 63;
  int wm = wid >> 1, wn = wid & 1;
  int tile_row = blockIdx.x * 128;
  f32x4 acc[4][4] = {};
  int srow = lane >> 3;
  int scol = (lane & 7) * 8;
  for (int k0 = 0; k0 < K; k0 += BK) {
    __syncthreads();
    #pragma unroll
    for (int j=0; j<4; j++) {
      int seg = wid + j*4;            // 16 segments of 1KB per tile
      int r = seg*8 + srow;
      gload16(A + (size_t)(tile_row + r)*lda + (k0 + scol), &As[seg*512]);
      gload16(B + (size_t)r*ldb + (k0 + scol), &Bs[seg*512]);
    }
    __syncthreads();                  // compiler drains vmcnt before barrier
    #pragma unroll
    for (int kk=0; kk<2; kk++) {
      bf16x8 af[4], bfr[4];
      #pragma unroll
      for (int mt=0; mt<4; mt++)
        af[mt] = *(const bf16x8*)&As[(wm*64 + mt*16 + (lane&15))*BK + kk*32 + ((lane>>4)*8)];
      #pragma unroll
      for (int nt=0; nt<4; nt++)
        bfr[nt] = *(const bf16x8*)&Bs[(wn*64 + nt*16 + (lane&15))*BK + kk*32 + ((lane>>4)*8)];
      #pragma unroll
      for (int mt=0; mt<4; mt++)
        #pragma unroll
        for (int nt=0; nt<4; nt++)
          acc[mt][nt] = __builtin_amdgcn_mfma_f32_16x16x32_bf16(af[mt], bfr[nt], acc[mt][nt], 0, 0, 0);
    }
  }
  #pragma unroll
  for (int mt=0; mt<4; mt++) {
    int rb = tile_row + wm*64 + mt*16 + ((lane>>4)<<2);
    #pragma unroll
    for (int nt=0; nt<4; nt++) {
      int gc = wn*64 + nt*16 + (lane&15);
      #pragma unroll
      for (int r=0; r<4; r++) {
        int grow = row0_abs + rb + r;
        if (grow < NN) Cbf[(size_t)grow*DD + gc] = (u16)f2bf(acc[mt][nt][r]);
      }
    }
  }
}

__global__ __launch_bounds__(256) void k_gn1(const unsigned* __restrict__ t,
    const float* __restrict__ w, const float* __restrict__ b, unsigned* __restrict__ hbf) {
  int wid = threadIdx.x >> 6, lane = threadIdx.x & 63;
  int row = blockIdx.x*4 + wid;
  if (row >= NN) return;
  unsigned w2 = t[(size_t)row*64 + lane];
  float x0 = bflo(w2), x1 = bfhi(w2);
  float s = x0 + x1, sq = x0*x0 + x1*x1;
  for (int d=1; d<64; d<<=1) { s += __shfl_xor(s, d); sq += __shfl_xor(sq, d); }
  float mu = s*(1.f/DD), var = sq*(1.f/DD) - mu*mu;
  float rs = rsqrtf(var + 1e-5f);
  float2 wv = ((const float2*)w)[lane], bv = ((const float2*)b)[lane];
  float y0 = fmaxf(fmaf((x0-mu)*rs, wv.x, bv.x), 0.f);
  float y1 = fmaxf(fmaf((x1-mu)*rs, wv.y, bv.y), 0.f);
  hbf[(size_t)row*64 + lane] = f2bf(y0) | (f2bf(y1) << 16);
}

__global__ __launch_bounds__(256) void k_gn2(const unsigned* __restrict__ h2,
    const float* __restrict__ w, const float* __restrict__ b,
    const float* __restrict__ res, float* __restrict__ out32,
    unsigned* __restrict__ featbf) {
  int wid = threadIdx.x >> 6, lane = threadIdx.x & 63;
  int row = blockIdx.x*4 + wid;
  if (row >= NN) return;
  unsigned w2 = h2[(size_t)row*64 + lane];
  float x0 = bflo(w2), x1 = bfhi(w2);
  float s = x0 + x1, sq = x0*x0 + x1*x1;
  for (int d=1; d<64; d<<=1) { s += __shfl_xor(s, d); sq += __shfl_xor(sq, d); }
  float mu = s*(1.f/DD), var = sq*(1.f/DD) - mu*mu;
  float rs = rsqrtf(var + 1e-5f);
  float2 wv = ((const float2*)w)[lane], bv = ((const float2*)b)[lane];
  float2 rv = ((const float2*)(res + (size_t)row*DD))[lane];
  float o0 = fmaxf(fmaf((x0-mu)*rs, wv.x, bv.x) + rv.x, 0.f);
  float o1 = fmaxf(fmaf((x1-mu)*rs, wv.y, bv.y) + rv.y, 0.f);
  ((float2*)(out32 + (size_t)row*DD))[lane] = make_float2(o0, o1);
  featbf[(size_t)row*64 + lane] = f2bf(o0) | (f2bf(o1) << 16);
}

extern "C" void kernel_launch(void* const* d_in, const int* in_sizes, int n_in,
                              void* d_out, int out_size, void* d_ws, size_t ws_size,
                              hipStream_t stream) {
  const float* feat_in = (const float*)d_in[0];
  const int* pre_u  = (const int*)d_in[1];
  const int* pre_v  = (const int*)d_in[2];
  const int* suc_u  = (const int*)d_in[3];
  const int* suc_v  = (const int*)d_in[4];
  const int* left_u = (const int*)d_in[5];
  const int* left_v = (const int*)d_in[6];
  const int* right_u= (const int*)d_in[7];
  const int* right_v= (const int*)d_in[8];
  const float* W_ctr  = (const float*)d_in[9];
  const float* W_pre  = (const float*)d_in[10];
  const float* W_suc  = (const float*)d_in[11];
  const float* W_left = (const float*)d_in[12];
  const float* W_right= (const float*)d_in[13];
  const float* gn1w   = (const float*)d_in[14];
  const float* gn1b   = (const float*)d_in[15];
  const float* W_ctr2 = (const float*)d_in[16];
  const float* gn2w   = (const float*)d_in[17];
  const float* gn2b   = (const float*)d_in[18];

  char* ws = (char*)d_ws;
  size_t off = 0;
  auto alloc = [&](size_t bytes) -> char* {
    char* p = ws + off; off += (bytes + 255) & ~(size_t)255; return p;
  };
  float*    feat32 = (float*)   alloc((size_t)NN*DD*4);                 // 128.0 MB
  unsigned* featbf = (unsigned*)alloc((size_t)NN*64*4);                 //  64.0 MB
  unsigned* hbf    = (unsigned*)alloc((size_t)TILES_TOTAL*128*64*4);    //  64.0 MB (tile-padded)
  u16*      tempbf = (u16*)     alloc((size_t)TILES_TOTAL*128*DD*2);    //  64.0 MB (tile-padded)
  u16*      wcat   = (u16*)     alloc((size_t)128*KBIG*2);
  u16*      wc2    = (u16*)     alloc((size_t)128*128*2);
  int*      rowptr = (int*)     alloc((size_t)(M14+1)*4);
  int*      cursor = (int*)     alloc((size_t)M14*4);
  int*      edge_v = (int*)     alloc((size_t)TOTE*4);
  int*      bsums  = (int*)     alloc((size_t)NB1*4);

  // Xc panel: adaptive — use whatever workspace remains (round-1 abort was ws overflow).
  size_t tile_bytes = (size_t)128*KBIG*2;  // 480 KiB per 128-row tile
  size_t avail = (ws_size > off + 65536) ? (ws_size - off - 65536) : 0;
  int chunk_tiles = (int)(avail / tile_bytes);
  if (chunk_tiles > TILES_TOTAL) chunk_tiles = TILES_TOTAL;
  if (chunk_tiles < 8) chunk_tiles = 8;    // last resort
  unsigned* Xc = (unsigned*)alloc((size_t)chunk_tiles * tile_bytes);
  int nchunk = (TILES_TOTAL + chunk_tiles - 1) / chunk_tiles;
  (void)in_sizes; (void)n_in; (void)out_size;

  // ---- CSR build (edges are iteration-invariant) ----
  hipMemsetAsync(cursor, 0, (size_t)M14*4, stream);
  k_hist<<<(TOTE+255)/256, 256, 0, stream>>>(pre_u, suc_u, left_u, right_u, cursor);
  k_scanA<<<NB1, 256, 0, stream>>>(cursor, rowptr, bsums);
  k_scanB<<<1, 256, 0, stream>>>(bsums, NB1);
  k_scanC<<<NB1, 256, 0, stream>>>(rowptr, bsums);
  hipMemcpyAsync(cursor, rowptr, (size_t)M14*4, hipMemcpyDeviceToDevice, stream);
  k_fill<<<(TOTE+255)/256, 256, 0, stream>>>(pre_u, pre_v, suc_u, suc_v,
                                             left_u, left_v, right_u, right_v,
                                             cursor, edge_v);

  k_f2bf<<<NN*64/256, 256, 0, stream>>>(feat_in, featbf);

  for (int it = 0; it < NITER; it++) {
    k_bw<<<1024, 256, 0, stream>>>(W_ctr, W_pre, W_suc, W_left, W_right, W_ctr2, it, wcat, wc2);
    for (int c = 0; c < nchunk; c++) {
      int tile0 = c*chunk_tiles;
      int tiles = (TILES_TOTAL - tile0 < chunk_tiles) ? (TILES_TOTAL - tile0) : chunk_tiles;
      int base  = tile0*128;
      k_agg<<<dim3(tiles*32, 15), 256, 0, stream>>>(featbf, rowptr, edge_v, Xc, base);
      gemm_bt<<<tiles, 256, 0, stream>>>((const u16*)Xc, KBIG, wcat, KBIG, tempbf, KBIG, base);
    }
    k_gn1<<<(NN+3)/4, 256, 0, stream>>>((const unsigned*)tempbf, gn1w + it*DD, gn1b + it*DD, hbf);
    gemm_bt<<<TILES_TOTAL, 256, 0, stream>>>((const u16*)hbf, DD, wc2, DD, tempbf, DD, 0);
    k_gn2<<<(NN+3)/4, 256, 0, stream>>>((const unsigned*)tempbf, gn2w + it*DD, gn2b + it*DD,
        (it == 0 ? feat_in : feat32),
        (it == NITER-1 ? (float*)d_out : feat32), featbf);
  }
}

// Round 3
// 5484.864 us; speedup vs baseline: 1.3058x; 1.3058x over previous
//
#include <hip/hip_runtime.h>

// Net_32323923870241: graph fusion block, MI355X (gfx950)
// Round 3: CSR re-laid out [node][slot]; wave-per-node aggregation with
// coalesced edge preload + 4x-unrolled independent gathers.

#define NN 250000
#define DD 128
#define EE 500000
#define ELE 50000
#define NITER 4
#define NL 14
#define M14 (NL*NN)              // 3,500,000
#define TOTE (12*EE + 2*ELE)     // 6,100,000 edges
#define SCHUNK 2048
#define NB1 ((M14 + SCHUNK - 1)/SCHUNK)   // 1709
#define KBIG (15*DD)             // 1920
#define BK 64
#define TILES_TOTAL ((NN + 127)/128)      // 1954

typedef unsigned short u16;
typedef __attribute__((ext_vector_type(4))) float f32x4;
typedef __attribute__((ext_vector_type(8))) __bf16 bf16x8;

static __device__ __forceinline__ unsigned f2bf(float f) {
  unsigned u = __float_as_uint(f);
  return (u + 0x7fffu + ((u >> 16) & 1u)) >> 16;   // RNE
}
static __device__ __forceinline__ float bflo(unsigned w){ return __uint_as_float(w << 16); }
static __device__ __forceinline__ float bfhi(unsigned w){ return __uint_as_float(w & 0xffff0000u); }

static __device__ __forceinline__ void gload16(const u16* g, u16* l) {
  __builtin_amdgcn_global_load_lds(
      (const __attribute__((address_space(1))) void*)g,
      (__attribute__((address_space(3))) void*)l, 16, 0, 0);
}

// ---------------- CSR build (layout: cnt/rowptr[node*NL + list]) ----------------
__global__ void k_hist(const int* __restrict__ pu, const int* __restrict__ su,
                       const int* __restrict__ lu, const int* __restrict__ ru,
                       int* __restrict__ cnt) {
  int idx = blockIdx.x*256 + threadIdx.x;
  if (idx >= TOTE) return;
  int l, u;
  if (idx < 12*EE) {
    l = idx / EE; int e = idx - l*EE;
    u = (l < 6) ? pu[l*EE + e] : su[(l-6)*EE + e];
  } else {
    int r = idx - 12*EE;
    if (r < ELE) { l = 12; u = lu[r]; }
    else         { l = 13; u = ru[r - ELE]; }
  }
  atomicAdd(&cnt[u*NL + l], 1);
}

__global__ void k_scanA(const int* __restrict__ in, int* __restrict__ out, int* __restrict__ bsums) {
  __shared__ int lds[256];
  int t = threadIdx.x;
  int base = blockIdx.x*SCHUNK + t*8;
  int v[8]; int s = 0;
  #pragma unroll
  for (int j=0;j<8;j++){ int x = (base+j < M14) ? in[base+j] : 0; v[j] = s; s += x; }
  lds[t] = s; __syncthreads();
  for (int d=1; d<256; d<<=1) {
    int add = (t>=d) ? lds[t-d] : 0; __syncthreads();
    lds[t] += add; __syncthreads();
  }
  int incl = lds[t];
  int excl = incl - s;
  if (t == 255) bsums[blockIdx.x] = incl;
  #pragma unroll
  for (int j=0;j<8;j++) if (base+j < M14) out[base+j] = excl + v[j];
}

__global__ void k_scanB(int* __restrict__ data, int n) {
  __shared__ int lds[256];
  __shared__ int carry;
  int t = threadIdx.x;
  if (t == 0) carry = 0;
  __syncthreads();
  for (int base=0; base<n; base+=256) {
    int i = base + t;
    int x = (i < n) ? data[i] : 0;
    lds[t] = x; __syncthreads();
    for (int d=1; d<256; d<<=1) {
      int add = (t>=d) ? lds[t-d] : 0; __syncthreads();
      lds[t] += add; __syncthreads();
    }
    int incl = lds[t];
    int c = carry;
    if (i < n) data[i] = c + incl - x;
    __syncthreads();
    if (t == 255) carry = c + incl;
    __syncthreads();
  }
}

__global__ void k_scanC(int* __restrict__ out, const int* __restrict__ bsums) {
  int t = threadIdx.x;
  int base = blockIdx.x*SCHUNK + t*8;
  int add = bsums[blockIdx.x];
  #pragma unroll
  for (int j=0;j<8;j++) if (base+j < M14) out[base+j] += add;
  if (blockIdx.x == 0 && t == 0) out[M14] = TOTE;
}

__global__ void k_fill(const int* __restrict__ pu, const int* __restrict__ pv,
                       const int* __restrict__ su, const int* __restrict__ sv,
                       const int* __restrict__ lu, const int* __restrict__ lv,
                       const int* __restrict__ ru, const int* __restrict__ rv,
                       int* __restrict__ cursor, int* __restrict__ edge_v) {
  int idx = blockIdx.x*256 + threadIdx.x;
  if (idx >= TOTE) return;
  int l, u, v;
  if (idx < 12*EE) {
    l = idx / EE; int e = idx - l*EE;
    if (l < 6) { u = pu[l*EE+e]; v = pv[l*EE+e]; }
    else       { u = su[(l-6)*EE+e]; v = sv[(l-6)*EE+e]; }
  } else {
    int r = idx - 12*EE;
    if (r < ELE) { l = 12; u = lu[r]; v = lv[r]; }
    else         { l = 13; u = ru[r-ELE]; v = rv[r-ELE]; }
  }
  int pos = atomicAdd(&cursor[u*NL + l], 1);
  edge_v[pos] = v;
}

// ---------------- per-iteration kernels ----------------
__global__ void k_f2bf(const float* __restrict__ in, unsigned* __restrict__ out) {
  int i = blockIdx.x*256 + threadIdx.x;   // grid sized exactly NN*64
  float2 v = ((const float2*)in)[i];
  out[i] = f2bf(v.x) | (f2bf(v.y) << 16);
}

__global__ void k_bw(const float* __restrict__ Wc, const float* __restrict__ Wp,
                     const float* __restrict__ Ws, const float* __restrict__ Wl,
                     const float* __restrict__ Wr, const float* __restrict__ Wc2,
                     int it, u16* __restrict__ wcat, u16* __restrict__ wc2) {
  int i = blockIdx.x*256 + threadIdx.x;
  if (i < 128*KBIG) {
    int r = i / KBIG, K = i - r*KBIG;
    int s = K >> 7, c = K & 127;
    float val;
    if (s == 0)       val = Wc[(it*128 + r)*128 + c];
    else if (s <= 6)  val = Wp[((it*6 + (s-1))*128 + r)*128 + c];
    else if (s <= 12) val = Ws[((it*6 + (s-7))*128 + r)*128 + c];
    else if (s == 13) val = Wl[(it*128 + r)*128 + c];
    else              val = Wr[(it*128 + r)*128 + c];
    wcat[i] = (u16)f2bf(val);
  } else {
    int j = i - 128*KBIG;  // < 16384
    wc2[j] = (u16)f2bf(Wc2[it*16384 + j]);
  }
}

// wave-per-node aggregation: slot 0 = self copy, slots 1..14 = CSR lists.
// Edges for a node are contiguous (node-major CSR) -> coalesced preload, then
// 4x-unrolled independent row gathers.
__global__ __launch_bounds__(256) void k_agg(const unsigned* __restrict__ featbf,
    const int* __restrict__ rowptr, const int* __restrict__ edge_v,
    unsigned* __restrict__ X, int chunk_base) {
  int wid = threadIdx.x >> 6, lane = threadIdx.x & 63;
  int nl = blockIdx.x*4 + wid;
  int node = chunk_base + nl;
  size_t xbase = (size_t)nl*(KBIG/2);
  if (node >= NN) {
    #pragma unroll
    for (int s=0; s<15; s++) X[xbase + s*64 + lane] = 0;
    return;
  }
  X[xbase + lane] = featbf[(size_t)node*64 + lane];   // slot 0: self
  int rp = 0;
  if (lane < NL+1) rp = rowptr[node*NL + lane];        // 15 bounds, contiguous
  #pragma unroll 1
  for (int s=0; s<NL; s++) {
    int st = __shfl(rp, s), en = __shfl(rp, s+1);
    float ax = 0.f, ay = 0.f;
    for (int e0 = st; e0 < en; e0 += 64) {
      int vv = 0;
      if (e0 + lane < en) vv = edge_v[e0 + lane];
      int cnt = en - e0; if (cnt > 64) cnt = 64;
      int i = 0;
      for (; i+4 <= cnt; i += 4) {
        int v0 = __shfl(vv, i), v1 = __shfl(vv, i+1);
        int v2 = __shfl(vv, i+2), v3 = __shfl(vv, i+3);
        unsigned w0 = featbf[(size_t)v0*64 + lane];
        unsigned w1 = featbf[(size_t)v1*64 + lane];
        unsigned w2 = featbf[(size_t)v2*64 + lane];
        unsigned w3 = featbf[(size_t)v3*64 + lane];
        ax += bflo(w0) + bflo(w1) + bflo(w2) + bflo(w3);
        ay += bfhi(w0) + bfhi(w1) + bfhi(w2) + bfhi(w3);
      }
      for (; i < cnt; i++) {
        int v = __shfl(vv, i);
        unsigned w = featbf[(size_t)v*64 + lane];
        ax += bflo(w); ay += bfhi(w);
      }
    }
    X[xbase + (s+1)*64 + lane] = f2bf(ax) | (f2bf(ay) << 16);
  }
}

// C[row][col] = sum_K A[row][K] * B[col][K]; output converted to bf16 (u16).
__global__ __launch_bounds__(256) void gemm_bt(
    const u16* __restrict__ A, int lda,
    const u16* __restrict__ B, int ldb,
    u16* __restrict__ Cbf, int K, int row0_abs) {
  __shared__ u16 As[128*BK];
  __shared__ u16 Bs[128*BK];
  int tid = threadIdx.x, wid = tid >> 6, lane = tid & 63;
  int wm = wid >> 1, wn = wid & 1;
  int tile_row = blockIdx.x * 128;
  f32x4 acc[4][4] = {};
  int srow = lane >> 3;
  int scol = (lane & 7) * 8;
  for (int k0 = 0; k0 < K; k0 += BK) {
    __syncthreads();
    #pragma unroll
    for (int j=0; j<4; j++) {
      int seg = wid + j*4;            // 16 segments of 1KB per tile
      int r = seg*8 + srow;
      gload16(A + (size_t)(tile_row + r)*lda + (k0 + scol), &As[seg*512]);
      gload16(B + (size_t)r*ldb + (k0 + scol), &Bs[seg*512]);
    }
    __syncthreads();
    #pragma unroll
    for (int kk=0; kk<2; kk++) {
      bf16x8 af[4], bfr[4];
      #pragma unroll
      for (int mt=0; mt<4; mt++)
        af[mt] = *(const bf16x8*)&As[(wm*64 + mt*16 + (lane&15))*BK + kk*32 + ((lane>>4)*8)];
      #pragma unroll
      for (int nt=0; nt<4; nt++)
        bfr[nt] = *(const bf16x8*)&Bs[(wn*64 + nt*16 + (lane&15))*BK + kk*32 + ((lane>>4)*8)];
      #pragma unroll
      for (int mt=0; mt<4; mt++)
        #pragma unroll
        for (int nt=0; nt<4; nt++)
          acc[mt][nt] = __builtin_amdgcn_mfma_f32_16x16x32_bf16(af[mt], bfr[nt], acc[mt][nt], 0, 0, 0);
    }
  }
  #pragma unroll
  for (int mt=0; mt<4; mt++) {
    int rb = tile_row + wm*64 + mt*16 + ((lane>>4)<<2);
    #pragma unroll
    for (int nt=0; nt<4; nt++) {
      int gc = wn*64 + nt*16 + (lane&15);
      #pragma unroll
      for (int r=0; r<4; r++) {
        int grow = row0_abs + rb + r;
        if (grow < NN) Cbf[(size_t)grow*DD + gc] = (u16)f2bf(acc[mt][nt][r]);
      }
    }
  }
}

__global__ __launch_bounds__(256) void k_gn1(const unsigned* __restrict__ t,
    const float* __restrict__ w, const float* __restrict__ b, unsigned* __restrict__ hbf) {
  int wid = threadIdx.x >> 6, lane = threadIdx.x & 63;
  int row = blockIdx.x*4 + wid;
  if (row >= NN) return;
  unsigned w2 = t[(size_t)row*64 + lane];
  float x0 = bflo(w2), x1 = bfhi(w2);
  float s = x0 + x1, sq = x0*x0 + x1*x1;
  for (int d=1; d<64; d<<=1) { s += __shfl_xor(s, d); sq += __shfl_xor(sq, d); }
  float mu = s*(1.f/DD), var = sq*(1.f/DD) - mu*mu;
  float rs = rsqrtf(var + 1e-5f);
  float2 wv = ((const float2*)w)[lane], bv = ((const float2*)b)[lane];
  float y0 = fmaxf(fmaf((x0-mu)*rs, wv.x, bv.x), 0.f);
  float y1 = fmaxf(fmaf((x1-mu)*rs, wv.y, bv.y), 0.f);
  hbf[(size_t)row*64 + lane] = f2bf(y0) | (f2bf(y1) << 16);
}

__global__ __launch_bounds__(256) void k_gn2(const unsigned* __restrict__ h2,
    const float* __restrict__ w, const float* __restrict__ b,
    const float* __restrict__ res, float* __restrict__ out32,
    unsigned* __restrict__ featbf) {
  int wid = threadIdx.x >> 6, lane = threadIdx.x & 63;
  int row = blockIdx.x*4 + wid;
  if (row >= NN) return;
  unsigned w2 = h2[(size_t)row*64 + lane];
  float x0 = bflo(w2), x1 = bfhi(w2);
  float s = x0 + x1, sq = x0*x0 + x1*x1;
  for (int d=1; d<64; d<<=1) { s += __shfl_xor(s, d); sq += __shfl_xor(sq, d); }
  float mu = s*(1.f/DD), var = sq*(1.f/DD) - mu*mu;
  float rs = rsqrtf(var + 1e-5f);
  float2 wv = ((const float2*)w)[lane], bv = ((const float2*)b)[lane];
  float2 rv = ((const float2*)(res + (size_t)row*DD))[lane];
  float o0 = fmaxf(fmaf((x0-mu)*rs, wv.x, bv.x) + rv.x, 0.f);
  float o1 = fmaxf(fmaf((x1-mu)*rs, wv.y, bv.y) + rv.y, 0.f);
  ((float2*)(out32 + (size_t)row*DD))[lane] = make_float2(o0, o1);
  featbf[(size_t)row*64 + lane] = f2bf(o0) | (f2bf(o1) << 16);
}

extern "C" void kernel_launch(void* const* d_in, const int* in_sizes, int n_in,
                              void* d_out, int out_size, void* d_ws, size_t ws_size,
                              hipStream_t stream) {
  const float* feat_in = (const float*)d_in[0];
  const int* pre_u  = (const int*)d_in[1];
  const int* pre_v  = (const int*)d_in[2];
  const int* suc_u  = (const int*)d_in[3];
  const int* suc_v  = (const int*)d_in[4];
  const int* left_u = (const int*)d_in[5];
  const int* left_v = (const int*)d_in[6];
  const int* right_u= (const int*)d_in[7];
  const int* right_v= (const int*)d_in[8];
  const float* W_ctr  = (const float*)d_in[9];
  const float* W_pre  = (const float*)d_in[10];
  const float* W_suc  = (const float*)d_in[11];
  const float* W_left = (const float*)d_in[12];
  const float* W_right= (const float*)d_in[13];
  const float* gn1w   = (const float*)d_in[14];
  const float* gn1b   = (const float*)d_in[15];
  const float* W_ctr2 = (const float*)d_in[16];
  const float* gn2w   = (const float*)d_in[17];
  const float* gn2b   = (const float*)d_in[18];

  char* ws = (char*)d_ws;
  size_t off = 0;
  auto alloc = [&](size_t bytes) -> char* {
    char* p = ws + off; off += (bytes + 255) & ~(size_t)255; return p;
  };
  float*    feat32 = (float*)   alloc((size_t)NN*DD*4);                 // 128.0 MB
  unsigned* featbf = (unsigned*)alloc((size_t)NN*64*4);                 //  64.0 MB
  unsigned* hbf    = (unsigned*)alloc((size_t)TILES_TOTAL*128*64*4);    //  64.0 MB (tile-padded)
  u16*      tempbf = (u16*)     alloc((size_t)TILES_TOTAL*128*DD*2);    //  64.0 MB (tile-padded)
  u16*      wcat   = (u16*)     alloc((size_t)128*KBIG*2);
  u16*      wc2    = (u16*)     alloc((size_t)128*128*2);
  int*      rowptr = (int*)     alloc((size_t)(M14+1)*4);
  int*      cursor = (int*)     alloc((size_t)M14*4);
  int*      edge_v = (int*)     alloc((size_t)TOTE*4);
  int*      bsums  = (int*)     alloc((size_t)NB1*4);

  // Xc panel: adaptive — use whatever workspace remains.
  size_t tile_bytes = (size_t)128*KBIG*2;  // 480 KiB per 128-row tile
  size_t avail = (ws_size > off + 65536) ? (ws_size - off - 65536) : 0;
  int chunk_tiles = (int)(avail / tile_bytes);
  if (chunk_tiles > TILES_TOTAL) chunk_tiles = TILES_TOTAL;
  if (chunk_tiles < 8) chunk_tiles = 8;    // last resort
  unsigned* Xc = (unsigned*)alloc((size_t)chunk_tiles * tile_bytes);
  int nchunk = (TILES_TOTAL + chunk_tiles - 1) / chunk_tiles;
  (void)in_sizes; (void)n_in; (void)out_size;

  // ---- CSR build (edges are iteration-invariant) ----
  hipMemsetAsync(cursor, 0, (size_t)M14*4, stream);
  k_hist<<<(TOTE+255)/256, 256, 0, stream>>>(pre_u, suc_u, left_u, right_u, cursor);
  k_scanA<<<NB1, 256, 0, stream>>>(cursor, rowptr, bsums);
  k_scanB<<<1, 256, 0, stream>>>(bsums, NB1);
  k_scanC<<<NB1, 256, 0, stream>>>(rowptr, bsums);
  hipMemcpyAsync(cursor, rowptr, (size_t)M14*4, hipMemcpyDeviceToDevice, stream);
  k_fill<<<(TOTE+255)/256, 256, 0, stream>>>(pre_u, pre_v, suc_u, suc_v,
                                             left_u, left_v, right_u, right_v,
                                             cursor, edge_v);

  k_f2bf<<<NN*64/256, 256, 0, stream>>>(feat_in, featbf);

  for (int it = 0; it < NITER; it++) {
    k_bw<<<1024, 256, 0, stream>>>(W_ctr, W_pre, W_suc, W_left, W_right, W_ctr2, it, wcat, wc2);
    for (int c = 0; c < nchunk; c++) {
      int tile0 = c*chunk_tiles;
      int tiles = (TILES_TOTAL - tile0 < chunk_tiles) ? (TILES_TOTAL - tile0) : chunk_tiles;
      int base  = tile0*128;
      k_agg<<<tiles*32, 256, 0, stream>>>(featbf, rowptr, edge_v, Xc, base);
      gemm_bt<<<tiles, 256, 0, stream>>>((const u16*)Xc, KBIG, wcat, KBIG, tempbf, KBIG, base);
    }
    k_gn1<<<(NN+3)/4, 256, 0, stream>>>((const unsigned*)tempbf, gn1w + it*DD, gn1b + it*DD, hbf);
    gemm_bt<<<TILES_TOTAL, 256, 0, stream>>>((const u16*)hbf, DD, wc2, DD, tempbf, DD, 0);
    k_gn2<<<(NN+3)/4, 256, 0, stream>>>((const unsigned*)tempbf, gn2w + it*DD, gn2b + it*DD,
        (it == 0 ? feat_in : feat32),
        (it == NITER-1 ? (float*)d_out : feat32), featbf);
  }
}

// Round 4
// 5032.028 us; speedup vs baseline: 1.4233x; 1.0900x over previous
//
#include <hip/hip_runtime.h>

// Net_32323923870241: graph fusion block, MI355X (gfx950)
// Round 4: bucketed counting-sort CSR (kills scatter write-amplification),
// GN fused into GEMM epilogues, slot-0 read direct from featbf,
// 8-deep pipelined gather in k_agg.

#define NN 250000
#define DD 128
#define EE 500000
#define ELE 50000
#define NITER 4
#define NL 14
#define M14 (NL*NN)              // 3,500,000
#define TOTE (12*EE + 2*ELE)     // 6,100,000 edges
#define KBIG (15*DD)             // 1920
#define BK 64
#define TILES_TOTAL ((NN + 127)/128)      // 1954
#define NBKT TILES_TOTAL
#define BCAP 4096
#define LK (128*NL)              // 1792 local keys per bucket

typedef unsigned short u16;
typedef __attribute__((ext_vector_type(4))) float f32x4;
typedef __attribute__((ext_vector_type(8))) __bf16 bf16x8;

static __device__ __forceinline__ unsigned f2bf(float f) {
  unsigned u = __float_as_uint(f);
  return (u + 0x7fffu + ((u >> 16) & 1u)) >> 16;   // RNE
}
static __device__ __forceinline__ float bflo(unsigned w){ return __uint_as_float(w << 16); }
static __device__ __forceinline__ float bfhi(unsigned w){ return __uint_as_float(w & 0xffff0000u); }

static __device__ __forceinline__ void gload16(const u16* g, u16* l) {
  __builtin_amdgcn_global_load_lds(
      (const __attribute__((address_space(1))) void*)g,
      (__attribute__((address_space(3))) void*)l, 16, 0, 0);
}

// ---------------- CSR build: bucketed counting sort ----------------
__global__ void k_bucket(const int* __restrict__ pu, const int* __restrict__ pv,
                         const int* __restrict__ su, const int* __restrict__ sv,
                         const int* __restrict__ lu, const int* __restrict__ lv,
                         const int* __restrict__ ru, const int* __restrict__ rv,
                         int* __restrict__ bcur, unsigned* __restrict__ bstage) {
  int idx = blockIdx.x*256 + threadIdx.x;
  if (idx >= TOTE) return;
  int l, u, v;
  if (idx < 12*EE) {
    l = idx / EE; int e = idx - l*EE;
    if (l < 6) { u = pu[l*EE+e]; v = pv[l*EE+e]; }
    else       { u = su[(l-6)*EE+e]; v = sv[(l-6)*EE+e]; }
  } else {
    int r = idx - 12*EE;
    if (r < ELE) { l = 12; u = lu[r]; v = lv[r]; }
    else         { l = 13; u = ru[r-ELE]; v = rv[r-ELE]; }
  }
  int b = u >> 7;
  unsigned rec = ((unsigned)((u & 127)*NL + l) << 18) | (unsigned)v;
  int pos = atomicAdd(&bcur[b], 1);
  if (pos < BCAP) bstage[(size_t)b*BCAP + pos] = rec;
}

__global__ void k_bscan(const int* __restrict__ bcur, int* __restrict__ bbase,
                        int* __restrict__ rowptr) {
  __shared__ int wsum[4];
  int t = threadIdx.x, lane = t & 63, w = t >> 6;
  int v[8]; int s = 0;
  #pragma unroll
  for (int j=0;j<8;j++){
    int idx = t*8 + j;
    int x = 0;
    if (idx < NBKT) { x = bcur[idx]; if (x > BCAP) x = BCAP; }
    v[j] = s; s += x;
  }
  int ps = s;
  for (int d=1; d<64; d<<=1) { int o = __shfl_up(ps, d); if (lane >= d) ps += o; }
  if (lane == 63) wsum[w] = ps;
  __syncthreads();
  int woff = 0;
  for (int j=0;j<w;j++) woff += wsum[j];
  int excl = woff + ps - s;
  #pragma unroll
  for (int j=0;j<8;j++){
    int idx = t*8 + j;
    if (idx < NBKT) bbase[idx] = excl + v[j];
  }
  if (t == 255) rowptr[M14] = excl + s;
}

// one block per bucket: local hist + scan -> rowptr + placed edges
__global__ __launch_bounds__(256) void k_place(const unsigned* __restrict__ bstage,
    const int* __restrict__ bcur, const int* __restrict__ bbase,
    int* __restrict__ rowptr, int* __restrict__ edge_v) {
  __shared__ int lh[LK];
  __shared__ int lex[LK];
  __shared__ int wsum[4];
  int b = blockIdx.x, t = threadIdx.x;
  int lane = t & 63, w = t >> 6;
  int cnt = bcur[b]; if (cnt > BCAP) cnt = BCAP;
  int base = bbase[b];
  const unsigned* rec = bstage + (size_t)b*BCAP;
  for (int i=t; i<LK; i+=256) lh[i] = 0;
  __syncthreads();
  for (int e=t; e<cnt; e+=256) atomicAdd(&lh[rec[e]>>18], 1);
  __syncthreads();
  // exclusive scan over LK=1792 = 256*7
  int s = 0;
  int my[7];
  #pragma unroll
  for (int j=0;j<7;j++){ my[j] = s; s += lh[t*7+j]; }
  int ps = s;
  for (int d=1; d<64; d<<=1) { int o = __shfl_up(ps, d); if (lane >= d) ps += o; }
  if (lane == 63) wsum[w] = ps;
  __syncthreads();
  int woff = 0;
  for (int j=0;j<w;j++) woff += wsum[j];
  int excl = woff + ps - s;
  #pragma unroll
  for (int j=0;j<7;j++) lex[t*7+j] = excl + my[j];
  __syncthreads();
  for (int i=t; i<LK; i+=256) rowptr[(size_t)b*LK + i] = base + lex[i];
  for (int i=t; i<LK; i+=256) lh[i] = lex[i];
  __syncthreads();
  for (int e=t; e<cnt; e+=256) {
    unsigned r = rec[e];
    int pos = atomicAdd(&lh[r>>18], 1);
    edge_v[base + pos] = (int)(r & 0x3FFFFu);
  }
}

// ---------------- per-iteration kernels ----------------
__global__ void k_f2bf(const float* __restrict__ in, unsigned* __restrict__ out) {
  int i = blockIdx.x*256 + threadIdx.x;   // grid sized exactly NN*64
  float2 v = ((const float2*)in)[i];
  out[i] = f2bf(v.x) | (f2bf(v.y) << 16);
}

__global__ void k_bw(const float* __restrict__ Wc, const float* __restrict__ Wp,
                     const float* __restrict__ Ws, const float* __restrict__ Wl,
                     const float* __restrict__ Wr, const float* __restrict__ Wc2,
                     int it, u16* __restrict__ wcat, u16* __restrict__ wc2) {
  int i = blockIdx.x*256 + threadIdx.x;
  if (i < 128*KBIG) {
    int r = i / KBIG, K = i - r*KBIG;
    int s = K >> 7, c = K & 127;
    float val;
    if (s == 0)       val = Wc[(it*128 + r)*128 + c];
    else if (s <= 6)  val = Wp[((it*6 + (s-1))*128 + r)*128 + c];
    else if (s <= 12) val = Ws[((it*6 + (s-7))*128 + r)*128 + c];
    else if (s == 13) val = Wl[(it*128 + r)*128 + c];
    else              val = Wr[(it*128 + r)*128 + c];
    wcat[i] = (u16)f2bf(val);
  } else {
    int j = i - 128*KBIG;  // < 16384
    wc2[j] = (u16)f2bf(Wc2[it*16384 + j]);
  }
}

// wave-per-node aggregation over 14 CSR lists; 8-deep independent gathers,
// uniform boundary-walk distributes rows to slot accumulators.
__global__ __launch_bounds__(256) void k_agg(const unsigned* __restrict__ featbf,
    const int* __restrict__ rowptr, const int* __restrict__ edge_v,
    unsigned* __restrict__ X, int chunk_base) {
  int wid = threadIdx.x >> 6, lane = threadIdx.x & 63;
  int nl = blockIdx.x*4 + wid;
  int node = chunk_base + nl;
  size_t xb = (size_t)nl * (14*64);
  if (node >= NN) {
    #pragma unroll
    for (int s=0;s<14;s++) X[xb + s*64 + lane] = 0;
    return;
  }
  int rp = 0;
  if (lane < 15) rp = rowptr[node*NL + lane];
  int st0 = __shfl(rp, 0);
  int cnt = __shfl(rp, 14) - st0;
  float ax = 0.f, ay = 0.f;
  int s = 0;
  int nextb = __shfl(rp, 1);
  int vv = 0;
  for (int base = 0; base < cnt; base += 8) {
    if ((base & 63) == 0) vv = edge_v[st0 + base + lane];
    unsigned wrow[8];
    int m = cnt - base; if (m > 8) m = 8;
    #pragma unroll
    for (int q=0;q<8;q++)
      if (q < m) {
        int v = __shfl(vv, (base & 63) + q);
        wrow[q] = featbf[(size_t)v*64 + lane];
      }
    for (int q=0;q<m;q++) {
      int e = st0 + base + q;
      while (e == nextb && s < 14) {
        X[xb + s*64 + lane] = f2bf(ax) | (f2bf(ay) << 16);
        ax = 0.f; ay = 0.f; s++;
        int ni = s + 1; if (ni > 14) ni = 14;
        nextb = __shfl(rp, ni);
      }
      ax += bflo(wrow[q]); ay += bfhi(wrow[q]);
    }
  }
  while (s < 14) {
    X[xb + s*64 + lane] = f2bf(ax) | (f2bf(ay) << 16);
    ax = 0.f; ay = 0.f; s++;
  }
}

// GEMM1: temp = [featbf | Xc] @ wcat^T, fused GroupNorm+ReLU -> hbf (bf16x2)
__global__ __launch_bounds__(256) void gemm_big(
    const u16* __restrict__ Xc, const u16* __restrict__ fbf,
    const u16* __restrict__ B, unsigned* __restrict__ hbf,
    const float* __restrict__ gw, const float* __restrict__ gb, int row0_abs) {
  __shared__ u16 smem[2*128*BK];
  u16* As = smem; u16* Bs = smem + 128*BK;
  int tid = threadIdx.x, wid = tid >> 6, lane = tid & 63;
  int wm = wid >> 1, wn = wid & 1;
  int tile_row = blockIdx.x * 128;
  f32x4 acc[4][4] = {};
  int srow = lane >> 3, scol = (lane & 7) * 8;
  for (int k0 = 0; k0 < KBIG; k0 += BK) {
    __syncthreads();
    if (k0 < DD) {
      #pragma unroll
      for (int j=0;j<4;j++) {
        int seg = wid + j*4; int r = seg*8 + srow;
        int arow = row0_abs + tile_row + r; if (arow > NN-1) arow = NN-1;
        gload16(fbf + (size_t)arow*DD + (k0 + scol), &As[seg*512]);
        gload16(B + (size_t)r*KBIG + (k0 + scol), &Bs[seg*512]);
      }
    } else {
      #pragma unroll
      for (int j=0;j<4;j++) {
        int seg = wid + j*4; int r = seg*8 + srow;
        gload16(Xc + (size_t)(tile_row + r)*(14*128) + (k0 - DD + scol), &As[seg*512]);
        gload16(B + (size_t)r*KBIG + (k0 + scol), &Bs[seg*512]);
      }
    }
    __syncthreads();
    #pragma unroll
    for (int kk=0; kk<2; kk++) {
      bf16x8 af[4], bfr[4];
      #pragma unroll
      for (int mt=0; mt<4; mt++)
        af[mt] = *(const bf16x8*)&As[(wm*64 + mt*16 + (lane&15))*BK + kk*32 + ((lane>>4)*8)];
      #pragma unroll
      for (int nt=0; nt<4; nt++)
        bfr[nt] = *(const bf16x8*)&Bs[(wn*64 + nt*16 + (lane&15))*BK + kk*32 + ((lane>>4)*8)];
      #pragma unroll
      for (int mt=0; mt<4; mt++)
        #pragma unroll
        for (int nt=0; nt<4; nt++)
          acc[mt][nt] = __builtin_amdgcn_mfma_f32_16x16x32_bf16(af[mt], bfr[nt], acc[mt][nt], 0, 0, 0);
    }
  }
  // fused GN1+ReLU epilogue: two 64-row phases through LDS
  float* Cs = (float*)smem;
  float2 wv = ((const float2*)gw)[lane];
  float2 bv = ((const float2*)gb)[lane];
  #pragma unroll
  for (int ph=0; ph<2; ph++) {
    __syncthreads();
    if (wm == ph) {
      #pragma unroll
      for (int mt=0;mt<4;mt++)
        #pragma unroll
        for (int nt=0;nt<4;nt++)
          #pragma unroll
          for (int r=0;r<4;r++)
            Cs[(size_t)(mt*16 + ((lane>>4)<<2) + r)*128 + wn*64 + nt*16 + (lane&15)] = acc[mt][nt][r];
    }
    __syncthreads();
    for (int rr=0; rr<16; rr++) {
      int lrow = wid*16 + rr;
      int grow = row0_abs + tile_row + ph*64 + lrow;
      float2 x = ((float2*)(Cs + lrow*128))[lane];
      float s = x.x + x.y, sq = x.x*x.x + x.y*x.y;
      #pragma unroll
      for (int d=1; d<64; d<<=1) { s += __shfl_xor(s,d); sq += __shfl_xor(sq,d); }
      float mu = s*(1.f/DD), var = sq*(1.f/DD) - mu*mu;
      float rs = rsqrtf(var + 1e-5f);
      if (grow < NN) {
        float y0 = fmaxf(fmaf((x.x-mu)*rs, wv.x, bv.x), 0.f);
        float y1 = fmaxf(fmaf((x.y-mu)*rs, wv.y, bv.y), 0.f);
        hbf[(size_t)grow*64 + lane] = f2bf(y0) | (f2bf(y1) << 16);
      }
    }
  }
}

// GEMM2: h2 = hbf @ wc2^T, fused GroupNorm + residual + ReLU -> out32 + featbf
__global__ __launch_bounds__(256) void gemm_sm(
    const u16* __restrict__ A, const u16* __restrict__ B,
    const float* __restrict__ res, float* __restrict__ out32,
    unsigned* __restrict__ featbf,
    const float* __restrict__ gw, const float* __restrict__ gb) {
  __shared__ u16 smem[2*128*BK];
  u16* As = smem; u16* Bs = smem + 128*BK;
  int tid = threadIdx.x, wid = tid >> 6, lane = tid & 63;
  int wm = wid >> 1, wn = wid & 1;
  int tile_row = blockIdx.x * 128;
  f32x4 acc[4][4] = {};
  int srow = lane >> 3, scol = (lane & 7) * 8;
  for (int k0 = 0; k0 < DD; k0 += BK) {
    __syncthreads();
    #pragma unroll
    for (int j=0;j<4;j++) {
      int seg = wid + j*4; int r = seg*8 + srow;
      gload16(A + (size_t)(tile_row + r)*DD + (k0 + scol), &As[seg*512]);
      gload16(B + (size_t)r*DD + (k0 + scol), &Bs[seg*512]);
    }
    __syncthreads();
    #pragma unroll
    for (int kk=0; kk<2; kk++) {
      bf16x8 af[4], bfr[4];
      #pragma unroll
      for (int mt=0; mt<4; mt++)
        af[mt] = *(const bf16x8*)&As[(wm*64 + mt*16 + (lane&15))*BK + kk*32 + ((lane>>4)*8)];
      #pragma unroll
      for (int nt=0; nt<4; nt++)
        bfr[nt] = *(const bf16x8*)&Bs[(wn*64 + nt*16 + (lane&15))*BK + kk*32 + ((lane>>4)*8)];
      #pragma unroll
      for (int mt=0; mt<4; mt++)
        #pragma unroll
        for (int nt=0; nt<4; nt++)
          acc[mt][nt] = __builtin_amdgcn_mfma_f32_16x16x32_bf16(af[mt], bfr[nt], acc[mt][nt], 0, 0, 0);
    }
  }
  // fused GN2 + residual + ReLU epilogue
  float* Cs = (float*)smem;
  float2 wv = ((const float2*)gw)[lane];
  float2 bv = ((const float2*)gb)[lane];
  #pragma unroll
  for (int ph=0; ph<2; ph++) {
    __syncthreads();
    if (wm == ph) {
      #pragma unroll
      for (int mt=0;mt<4;mt++)
        #pragma unroll
        for (int nt=0;nt<4;nt++)
          #pragma unroll
          for (int r=0;r<4;r++)
            Cs[(size_t)(mt*16 + ((lane>>4)<<2) + r)*128 + wn*64 + nt*16 + (lane&15)] = acc[mt][nt][r];
    }
    __syncthreads();
    for (int rr=0; rr<16; rr++) {
      int lrow = wid*16 + rr;
      int grow = tile_row + ph*64 + lrow;
      float2 x = ((float2*)(Cs + lrow*128))[lane];
      float s = x.x + x.y, sq = x.x*x.x + x.y*x.y;
      #pragma unroll
      for (int d=1; d<64; d<<=1) { s += __shfl_xor(s,d); sq += __shfl_xor(sq,d); }
      float mu = s*(1.f/DD), var = sq*(1.f/DD) - mu*mu;
      float rs = rsqrtf(var + 1e-5f);
      if (grow < NN) {
        float2 rv = ((const float2*)(res + (size_t)grow*DD))[lane];
        float o0 = fmaxf(fmaf((x.x-mu)*rs, wv.x, bv.x) + rv.x, 0.f);
        float o1 = fmaxf(fmaf((x.y-mu)*rs, wv.y, bv.y) + rv.y, 0.f);
        ((float2*)(out32 + (size_t)grow*DD))[lane] = make_float2(o0, o1);
        featbf[(size_t)grow*64 + lane] = f2bf(o0) | (f2bf(o1) << 16);
      }
    }
  }
}

extern "C" void kernel_launch(void* const* d_in, const int* in_sizes, int n_in,
                              void* d_out, int out_size, void* d_ws, size_t ws_size,
                              hipStream_t stream) {
  const float* feat_in = (const float*)d_in[0];
  const int* pre_u  = (const int*)d_in[1];
  const int* pre_v  = (const int*)d_in[2];
  const int* suc_u  = (const int*)d_in[3];
  const int* suc_v  = (const int*)d_in[4];
  const int* left_u = (const int*)d_in[5];
  const int* left_v = (const int*)d_in[6];
  const int* right_u= (const int*)d_in[7];
  const int* right_v= (const int*)d_in[8];
  const float* W_ctr  = (const float*)d_in[9];
  const float* W_pre  = (const float*)d_in[10];
  const float* W_suc  = (const float*)d_in[11];
  const float* W_left = (const float*)d_in[12];
  const float* W_right= (const float*)d_in[13];
  const float* gn1w   = (const float*)d_in[14];
  const float* gn1b   = (const float*)d_in[15];
  const float* W_ctr2 = (const float*)d_in[16];
  const float* gn2w   = (const float*)d_in[17];
  const float* gn2b   = (const float*)d_in[18];

  char* ws = (char*)d_ws;
  size_t off = 0;
  auto alloc = [&](size_t bytes) -> char* {
    char* p = ws + off; off += (bytes + 255) & ~(size_t)255; return p;
  };
  float*    feat32 = (float*)   alloc((size_t)NN*DD*4);                  // 128 MB
  unsigned* featbf = (unsigned*)alloc((size_t)NN*64*4);                  //  64 MB
  unsigned* hbf    = (unsigned*)alloc((size_t)TILES_TOTAL*128*64*4);     //  64 MB (pad)
  u16*      wcat   = (u16*)     alloc((size_t)128*KBIG*2);
  u16*      wc2    = (u16*)     alloc((size_t)128*128*2);
  int*      rowptr = (int*)     alloc(((size_t)NBKT*LK + 1)*4);          //  14 MB (pad nodes incl)
  int*      edge_v = (int*)     alloc((size_t)(TOTE + 64)*4);            //  24.4 MB
  unsigned* bstage = (unsigned*)alloc((size_t)NBKT*BCAP*4);              //  32 MB
  int*      bcur   = (int*)     alloc((size_t)NBKT*4);
  int*      bbase  = (int*)     alloc((size_t)NBKT*4);

  // Xc aggregation panel: adaptive, capped so chunk stays L3-resident.
  size_t tile_bytes = (size_t)128*(14*128)*2;   // 448 KiB per 128-row tile
  size_t avail = (ws_size > off + 65536) ? (ws_size - off - 65536) : 0;
  int chunk_tiles = (int)(avail / tile_bytes);
  if (chunk_tiles > 400) chunk_tiles = 400;     // ~175 MB, L3-friendly
  if (chunk_tiles < 8) chunk_tiles = 8;
  unsigned* Xc = (unsigned*)alloc((size_t)chunk_tiles * tile_bytes);
  int nchunk = (TILES_TOTAL + chunk_tiles - 1) / chunk_tiles;
  (void)in_sizes; (void)n_in; (void)out_size;

  // ---- CSR build (bucketed counting sort; edges iteration-invariant) ----
  hipMemsetAsync(bcur, 0, (size_t)NBKT*4, stream);
  k_bucket<<<(TOTE+255)/256, 256, 0, stream>>>(pre_u, pre_v, suc_u, suc_v,
                                               left_u, left_v, right_u, right_v,
                                               bcur, bstage);
  k_bscan<<<1, 256, 0, stream>>>(bcur, bbase, rowptr);
  k_place<<<NBKT, 256, 0, stream>>>(bstage, bcur, bbase, rowptr, edge_v);

  k_f2bf<<<NN*64/256, 256, 0, stream>>>(feat_in, featbf);

  for (int it = 0; it < NITER; it++) {
    k_bw<<<1024, 256, 0, stream>>>(W_ctr, W_pre, W_suc, W_left, W_right, W_ctr2, it, wcat, wc2);
    for (int c = 0; c < nchunk; c++) {
      int tile0 = c*chunk_tiles;
      int tiles = (TILES_TOTAL - tile0 < chunk_tiles) ? (TILES_TOTAL - tile0) : chunk_tiles;
      int base  = tile0*128;
      k_agg<<<tiles*32, 256, 0, stream>>>(featbf, rowptr, edge_v, Xc, base);
      gemm_big<<<tiles, 256, 0, stream>>>((const u16*)Xc, (const u16*)featbf, wcat,
                                          hbf, gn1w + it*DD, gn1b + it*DD, base);
    }
    gemm_sm<<<TILES_TOTAL, 256, 0, stream>>>((const u16*)hbf, wc2,
        (it == 0 ? feat_in : feat32),
        (it == NITER-1 ? (float*)d_out : feat32), featbf,
        gn2w + it*DD, gn2b + it*DD);
  }
}

// Round 5
// 4939.484 us; speedup vs baseline: 1.4500x; 1.0187x over previous
//
#include <hip/hip_runtime.h>

// Net_32323923870241: graph fusion block, MI355X (gfx950)
// Round 5: two-pass LDS-histogram binning for k_bucket (kills global-atomic
// serialization + write amplification). Xc chunk capped at 256 tiles for L3.

#define NN 250000
#define DD 128
#define EE 500000
#define ELE 50000
#define NITER 4
#define NL 14
#define M14 (NL*NN)              // 3,500,000
#define TOTE (12*EE + 2*ELE)     // 6,100,000 edges
#define KBIG (15*DD)             // 1920
#define BK 64
#define TILES_TOTAL ((NN + 127)/128)      // 1954
#define NBKT TILES_TOTAL
#define BCAP 4096
#define LK (128*NL)              // 1792 local keys per bucket
#define NBLK_BUCKET 256
#define EPB ((TOTE + NBLK_BUCKET - 1)/NBLK_BUCKET)   // 23829

typedef unsigned short u16;
typedef __attribute__((ext_vector_type(4))) float f32x4;
typedef __attribute__((ext_vector_type(8))) __bf16 bf16x8;

static __device__ __forceinline__ unsigned f2bf(float f) {
  unsigned u = __float_as_uint(f);
  return (u + 0x7fffu + ((u >> 16) & 1u)) >> 16;   // RNE
}
static __device__ __forceinline__ float bflo(unsigned w){ return __uint_as_float(w << 16); }
static __device__ __forceinline__ float bfhi(unsigned w){ return __uint_as_float(w & 0xffff0000u); }

static __device__ __forceinline__ void gload16(const u16* g, u16* l) {
  __builtin_amdgcn_global_load_lds(
      (const __attribute__((address_space(1))) void*)g,
      (__attribute__((address_space(3))) void*)l, 16, 0, 0);
}

static __device__ __forceinline__ int edge_u(int idx,
    const int* __restrict__ pu, const int* __restrict__ su,
    const int* __restrict__ lu, const int* __restrict__ ru) {
  if (idx < 12*EE) {
    int l = idx / EE; int e = idx - l*EE;
    return (l < 6) ? pu[l*EE + e] : su[(l-6)*EE + e];
  }
  int r = idx - 12*EE;
  return (r < ELE) ? lu[r] : ru[r - ELE];
}

static __device__ __forceinline__ void edge_luv(int idx,
    const int* __restrict__ pu, const int* __restrict__ pv,
    const int* __restrict__ su, const int* __restrict__ sv,
    const int* __restrict__ lu, const int* __restrict__ lv,
    const int* __restrict__ ru, const int* __restrict__ rv,
    int& l, int& u, int& v) {
  if (idx < 12*EE) {
    l = idx / EE; int e = idx - l*EE;
    if (l < 6) { u = pu[l*EE+e]; v = pv[l*EE+e]; }
    else       { u = su[(l-6)*EE+e]; v = sv[(l-6)*EE+e]; }
  } else {
    int r = idx - 12*EE;
    if (r < ELE) { l = 12; u = lu[r]; v = lv[r]; }
    else         { l = 13; u = ru[r-ELE]; v = rv[r-ELE]; }
  }
}

// ---------------- CSR build: two-pass LDS-histogram binning ----------------
__global__ __launch_bounds__(1024) void k_bucket(
    const int* __restrict__ pu, const int* __restrict__ pv,
    const int* __restrict__ su, const int* __restrict__ sv,
    const int* __restrict__ lu, const int* __restrict__ lv,
    const int* __restrict__ ru, const int* __restrict__ rv,
    int* __restrict__ bcur, unsigned* __restrict__ bstage) {
  __shared__ int cnt[NBKT];
  __shared__ int cur[NBKT];
  int t = threadIdx.x;
  for (int i=t; i<NBKT; i+=1024) cnt[i] = 0;
  __syncthreads();
  int e0 = blockIdx.x * EPB;
  int e1 = e0 + EPB; if (e1 > TOTE) e1 = TOTE;
  // pass 1: count (u only)
  for (int idx = e0 + t; idx < e1; idx += 1024) {
    int u = edge_u(idx, pu, su, lu, ru);
    atomicAdd(&cnt[u >> 7], 1);
  }
  __syncthreads();
  // reserve contiguous runs: one global atomic per nonempty bucket
  for (int i=t; i<NBKT; i+=1024) {
    int c = cnt[i];
    cur[i] = c ? atomicAdd(&bcur[i], c) : 0;
  }
  __syncthreads();
  // pass 2: place into this block's private runs
  for (int idx = e0 + t; idx < e1; idx += 1024) {
    int l, u, v;
    edge_luv(idx, pu, pv, su, sv, lu, lv, ru, rv, l, u, v);
    int b = u >> 7;
    unsigned rec = ((unsigned)((u & 127)*NL + l) << 18) | (unsigned)v;
    int pos = atomicAdd(&cur[b], 1);
    if (pos < BCAP) bstage[(size_t)b*BCAP + pos] = rec;
  }
}

__global__ void k_bscan(const int* __restrict__ bcur, int* __restrict__ bbase,
                        int* __restrict__ rowptr) {
  __shared__ int wsum[4];
  int t = threadIdx.x, lane = t & 63, w = t >> 6;
  int v[8]; int s = 0;
  #pragma unroll
  for (int j=0;j<8;j++){
    int idx = t*8 + j;
    int x = 0;
    if (idx < NBKT) { x = bcur[idx]; if (x > BCAP) x = BCAP; }
    v[j] = s; s += x;
  }
  int ps = s;
  for (int d=1; d<64; d<<=1) { int o = __shfl_up(ps, d); if (lane >= d) ps += o; }
  if (lane == 63) wsum[w] = ps;
  __syncthreads();
  int woff = 0;
  for (int j=0;j<w;j++) woff += wsum[j];
  int excl = woff + ps - s;
  #pragma unroll
  for (int j=0;j<8;j++){
    int idx = t*8 + j;
    if (idx < NBKT) bbase[idx] = excl + v[j];
  }
  if (t == 255) rowptr[M14] = excl + s;
}

// one block per bucket: local hist + scan -> rowptr + placed edges
__global__ __launch_bounds__(256) void k_place(const unsigned* __restrict__ bstage,
    const int* __restrict__ bcur, const int* __restrict__ bbase,
    int* __restrict__ rowptr, int* __restrict__ edge_v) {
  __shared__ int lh[LK];
  __shared__ int lex[LK];
  __shared__ int wsum[4];
  int b = blockIdx.x, t = threadIdx.x;
  int lane = t & 63, w = t >> 6;
  int cnt = bcur[b]; if (cnt > BCAP) cnt = BCAP;
  int base = bbase[b];
  const unsigned* rec = bstage + (size_t)b*BCAP;
  for (int i=t; i<LK; i+=256) lh[i] = 0;
  __syncthreads();
  for (int e=t; e<cnt; e+=256) atomicAdd(&lh[rec[e]>>18], 1);
  __syncthreads();
  // exclusive scan over LK=1792 = 256*7
  int s = 0;
  int my[7];
  #pragma unroll
  for (int j=0;j<7;j++){ my[j] = s; s += lh[t*7+j]; }
  int ps = s;
  for (int d=1; d<64; d<<=1) { int o = __shfl_up(ps, d); if (lane >= d) ps += o; }
  if (lane == 63) wsum[w] = ps;
  __syncthreads();
  int woff = 0;
  for (int j=0;j<w;j++) woff += wsum[j];
  int excl = woff + ps - s;
  #pragma unroll
  for (int j=0;j<7;j++) lex[t*7+j] = excl + my[j];
  __syncthreads();
  for (int i=t; i<LK; i+=256) rowptr[(size_t)b*LK + i] = base + lex[i];
  for (int i=t; i<LK; i+=256) lh[i] = lex[i];
  __syncthreads();
  for (int e=t; e<cnt; e+=256) {
    unsigned r = rec[e];
    int pos = atomicAdd(&lh[r>>18], 1);
    edge_v[base + pos] = (int)(r & 0x3FFFFu);
  }
}

// ---------------- per-iteration kernels ----------------
__global__ void k_f2bf(const float* __restrict__ in, unsigned* __restrict__ out) {
  int i = blockIdx.x*256 + threadIdx.x;   // grid sized exactly NN*64
  float2 v = ((const float2*)in)[i];
  out[i] = f2bf(v.x) | (f2bf(v.y) << 16);
}

__global__ void k_bw(const float* __restrict__ Wc, const float* __restrict__ Wp,
                     const float* __restrict__ Ws, const float* __restrict__ Wl,
                     const float* __restrict__ Wr, const float* __restrict__ Wc2,
                     int it, u16* __restrict__ wcat, u16* __restrict__ wc2) {
  int i = blockIdx.x*256 + threadIdx.x;
  if (i < 128*KBIG) {
    int r = i / KBIG, K = i - r*KBIG;
    int s = K >> 7, c = K & 127;
    float val;
    if (s == 0)       val = Wc[(it*128 + r)*128 + c];
    else if (s <= 6)  val = Wp[((it*6 + (s-1))*128 + r)*128 + c];
    else if (s <= 12) val = Ws[((it*6 + (s-7))*128 + r)*128 + c];
    else if (s == 13) val = Wl[(it*128 + r)*128 + c];
    else              val = Wr[(it*128 + r)*128 + c];
    wcat[i] = (u16)f2bf(val);
  } else {
    int j = i - 128*KBIG;  // < 16384
    wc2[j] = (u16)f2bf(Wc2[it*16384 + j]);
  }
}

// wave-per-node aggregation over 14 CSR lists; 8-deep independent gathers,
// uniform boundary-walk distributes rows to slot accumulators.
__global__ __launch_bounds__(256) void k_agg(const unsigned* __restrict__ featbf,
    const int* __restrict__ rowptr, const int* __restrict__ edge_v,
    unsigned* __restrict__ X, int chunk_base) {
  int wid = threadIdx.x >> 6, lane = threadIdx.x & 63;
  int nl = blockIdx.x*4 + wid;
  int node = chunk_base + nl;
  size_t xb = (size_t)nl * (14*64);
  if (node >= NN) {
    #pragma unroll
    for (int s=0;s<14;s++) X[xb + s*64 + lane] = 0;
    return;
  }
  int rp = 0;
  if (lane < 15) rp = rowptr[node*NL + lane];
  int st0 = __shfl(rp, 0);
  int cnt = __shfl(rp, 14) - st0;
  float ax = 0.f, ay = 0.f;
  int s = 0;
  int nextb = __shfl(rp, 1);
  int vv = 0;
  for (int base = 0; base < cnt; base += 8) {
    if ((base & 63) == 0) vv = edge_v[st0 + base + lane];
    unsigned wrow[8];
    int m = cnt - base; if (m > 8) m = 8;
    #pragma unroll
    for (int q=0;q<8;q++)
      if (q < m) {
        int v = __shfl(vv, (base & 63) + q);
        wrow[q] = featbf[(size_t)v*64 + lane];
      }
    for (int q=0;q<m;q++) {
      int e = st0 + base + q;
      while (e == nextb && s < 14) {
        X[xb + s*64 + lane] = f2bf(ax) | (f2bf(ay) << 16);
        ax = 0.f; ay = 0.f; s++;
        int ni = s + 1; if (ni > 14) ni = 14;
        nextb = __shfl(rp, ni);
      }
      ax += bflo(wrow[q]); ay += bfhi(wrow[q]);
    }
  }
  while (s < 14) {
    X[xb + s*64 + lane] = f2bf(ax) | (f2bf(ay) << 16);
    ax = 0.f; ay = 0.f; s++;
  }
}

// GEMM1: temp = [featbf | Xc] @ wcat^T, fused GroupNorm+ReLU -> hbf (bf16x2)
__global__ __launch_bounds__(256) void gemm_big(
    const u16* __restrict__ Xc, const u16* __restrict__ fbf,
    const u16* __restrict__ B, unsigned* __restrict__ hbf,
    const float* __restrict__ gw, const float* __restrict__ gb, int row0_abs) {
  __shared__ u16 smem[2*128*BK];
  u16* As = smem; u16* Bs = smem + 128*BK;
  int tid = threadIdx.x, wid = tid >> 6, lane = tid & 63;
  int wm = wid >> 1, wn = wid & 1;
  int tile_row = blockIdx.x * 128;
  f32x4 acc[4][4] = {};
  int srow = lane >> 3, scol = (lane & 7) * 8;
  for (int k0 = 0; k0 < KBIG; k0 += BK) {
    __syncthreads();
    if (k0 < DD) {
      #pragma unroll
      for (int j=0;j<4;j++) {
        int seg = wid + j*4; int r = seg*8 + srow;
        int arow = row0_abs + tile_row + r; if (arow > NN-1) arow = NN-1;
        gload16(fbf + (size_t)arow*DD + (k0 + scol), &As[seg*512]);
        gload16(B + (size_t)r*KBIG + (k0 + scol), &Bs[seg*512]);
      }
    } else {
      #pragma unroll
      for (int j=0;j<4;j++) {
        int seg = wid + j*4; int r = seg*8 + srow;
        gload16(Xc + (size_t)(tile_row + r)*(14*128) + (k0 - DD + scol), &As[seg*512]);
        gload16(B + (size_t)r*KBIG + (k0 + scol), &Bs[seg*512]);
      }
    }
    __syncthreads();
    #pragma unroll
    for (int kk=0; kk<2; kk++) {
      bf16x8 af[4], bfr[4];
      #pragma unroll
      for (int mt=0; mt<4; mt++)
        af[mt] = *(const bf16x8*)&As[(wm*64 + mt*16 + (lane&15))*BK + kk*32 + ((lane>>4)*8)];
      #pragma unroll
      for (int nt=0; nt<4; nt++)
        bfr[nt] = *(const bf16x8*)&Bs[(wn*64 + nt*16 + (lane&15))*BK + kk*32 + ((lane>>4)*8)];
      #pragma unroll
      for (int mt=0; mt<4; mt++)
        #pragma unroll
        for (int nt=0; nt<4; nt++)
          acc[mt][nt] = __builtin_amdgcn_mfma_f32_16x16x32_bf16(af[mt], bfr[nt], acc[mt][nt], 0, 0, 0);
    }
  }
  // fused GN1+ReLU epilogue: two 64-row phases through LDS
  float* Cs = (float*)smem;
  float2 wv = ((const float2*)gw)[lane];
  float2 bv = ((const float2*)gb)[lane];
  #pragma unroll
  for (int ph=0; ph<2; ph++) {
    __syncthreads();
    if (wm == ph) {
      #pragma unroll
      for (int mt=0;mt<4;mt++)
        #pragma unroll
        for (int nt=0;nt<4;nt++)
          #pragma unroll
          for (int r=0;r<4;r++)
            Cs[(size_t)(mt*16 + ((lane>>4)<<2) + r)*128 + wn*64 + nt*16 + (lane&15)] = acc[mt][nt][r];
    }
    __syncthreads();
    for (int rr=0; rr<16; rr++) {
      int lrow = wid*16 + rr;
      int grow = row0_abs + tile_row + ph*64 + lrow;
      float2 x = ((float2*)(Cs + lrow*128))[lane];
      float s = x.x + x.y, sq = x.x*x.x + x.y*x.y;
      #pragma unroll
      for (int d=1; d<64; d<<=1) { s += __shfl_xor(s,d); sq += __shfl_xor(sq,d); }
      float mu = s*(1.f/DD), var = sq*(1.f/DD) - mu*mu;
      float rs = rsqrtf(var + 1e-5f);
      if (grow < NN) {
        float y0 = fmaxf(fmaf((x.x-mu)*rs, wv.x, bv.x), 0.f);
        float y1 = fmaxf(fmaf((x.y-mu)*rs, wv.y, bv.y), 0.f);
        hbf[(size_t)grow*64 + lane] = f2bf(y0) | (f2bf(y1) << 16);
      }
    }
  }
}

// GEMM2: h2 = hbf @ wc2^T, fused GroupNorm + residual + ReLU -> out32 + featbf
__global__ __launch_bounds__(256) void gemm_sm(
    const u16* __restrict__ A, const u16* __restrict__ B,
    const float* __restrict__ res, float* __restrict__ out32,
    unsigned* __restrict__ featbf,
    const float* __restrict__ gw, const float* __restrict__ gb) {
  __shared__ u16 smem[2*128*BK];
  u16* As = smem; u16* Bs = smem + 128*BK;
  int tid = threadIdx.x, wid = tid >> 6, lane = tid & 63;
  int wm = wid >> 1, wn = wid & 1;
  int tile_row = blockIdx.x * 128;
  f32x4 acc[4][4] = {};
  int srow = lane >> 3, scol = (lane & 7) * 8;
  for (int k0 = 0; k0 < DD; k0 += BK) {
    __syncthreads();
    #pragma unroll
    for (int j=0;j<4;j++) {
      int seg = wid + j*4; int r = seg*8 + srow;
      gload16(A + (size_t)(tile_row + r)*DD + (k0 + scol), &As[seg*512]);
      gload16(B + (size_t)r*DD + (k0 + scol), &Bs[seg*512]);
    }
    __syncthreads();
    #pragma unroll
    for (int kk=0; kk<2; kk++) {
      bf16x8 af[4], bfr[4];
      #pragma unroll
      for (int mt=0; mt<4; mt++)
        af[mt] = *(const bf16x8*)&As[(wm*64 + mt*16 + (lane&15))*BK + kk*32 + ((lane>>4)*8)];
      #pragma unroll
      for (int nt=0; nt<4; nt++)
        bfr[nt] = *(const bf16x8*)&Bs[(wn*64 + nt*16 + (lane&15))*BK + kk*32 + ((lane>>4)*8)];
      #pragma unroll
      for (int mt=0; mt<4; mt++)
        #pragma unroll
        for (int nt=0; nt<4; nt++)
          acc[mt][nt] = __builtin_amdgcn_mfma_f32_16x16x32_bf16(af[mt], bfr[nt], acc[mt][nt], 0, 0, 0);
    }
  }
  // fused GN2 + residual + ReLU epilogue
  float* Cs = (float*)smem;
  float2 wv = ((const float2*)gw)[lane];
  float2 bv = ((const float2*)gb)[lane];
  #pragma unroll
  for (int ph=0; ph<2; ph++) {
    __syncthreads();
    if (wm == ph) {
      #pragma unroll
      for (int mt=0;mt<4;mt++)
        #pragma unroll
        for (int nt=0;nt<4;nt++)
          #pragma unroll
          for (int r=0;r<4;r++)
            Cs[(size_t)(mt*16 + ((lane>>4)<<2) + r)*128 + wn*64 + nt*16 + (lane&15)] = acc[mt][nt][r];
    }
    __syncthreads();
    for (int rr=0; rr<16; rr++) {
      int lrow = wid*16 + rr;
      int grow = tile_row + ph*64 + lrow;
      float2 x = ((float2*)(Cs + lrow*128))[lane];
      float s = x.x + x.y, sq = x.x*x.x + x.y*x.y;
      #pragma unroll
      for (int d=1; d<64; d<<=1) { s += __shfl_xor(s,d); sq += __shfl_xor(sq,d); }
      float mu = s*(1.f/DD), var = sq*(1.f/DD) - mu*mu;
      float rs = rsqrtf(var + 1e-5f);
      if (grow < NN) {
        float2 rv = ((const float2*)(res + (size_t)grow*DD))[lane];
        float o0 = fmaxf(fmaf((x.x-mu)*rs, wv.x, bv.x) + rv.x, 0.f);
        float o1 = fmaxf(fmaf((x.y-mu)*rs, wv.y, bv.y) + rv.y, 0.f);
        ((float2*)(out32 + (size_t)grow*DD))[lane] = make_float2(o0, o1);
        featbf[(size_t)grow*64 + lane] = f2bf(o0) | (f2bf(o1) << 16);
      }
    }
  }
}

extern "C" void kernel_launch(void* const* d_in, const int* in_sizes, int n_in,
                              void* d_out, int out_size, void* d_ws, size_t ws_size,
                              hipStream_t stream) {
  const float* feat_in = (const float*)d_in[0];
  const int* pre_u  = (const int*)d_in[1];
  const int* pre_v  = (const int*)d_in[2];
  const int* suc_u  = (const int*)d_in[3];
  const int* suc_v  = (const int*)d_in[4];
  const int* left_u = (const int*)d_in[5];
  const int* left_v = (const int*)d_in[6];
  const int* right_u= (const int*)d_in[7];
  const int* right_v= (const int*)d_in[8];
  const float* W_ctr  = (const float*)d_in[9];
  const float* W_pre  = (const float*)d_in[10];
  const float* W_suc  = (const float*)d_in[11];
  const float* W_left = (const float*)d_in[12];
  const float* W_right= (const float*)d_in[13];
  const float* gn1w   = (const float*)d_in[14];
  const float* gn1b   = (const float*)d_in[15];
  const float* W_ctr2 = (const float*)d_in[16];
  const float* gn2w   = (const float*)d_in[17];
  const float* gn2b   = (const float*)d_in[18];

  char* ws = (char*)d_ws;
  size_t off = 0;
  auto alloc = [&](size_t bytes) -> char* {
    char* p = ws + off; off += (bytes + 255) & ~(size_t)255; return p;
  };
  float*    feat32 = (float*)   alloc((size_t)NN*DD*4);                  // 128 MB
  unsigned* featbf = (unsigned*)alloc((size_t)NN*64*4);                  //  64 MB
  unsigned* hbf    = (unsigned*)alloc((size_t)TILES_TOTAL*128*64*4);     //  64 MB (pad)
  u16*      wcat   = (u16*)     alloc((size_t)128*KBIG*2);
  u16*      wc2    = (u16*)     alloc((size_t)128*128*2);
  int*      rowptr = (int*)     alloc(((size_t)NBKT*LK + 1)*4);          //  14 MB
  int*      edge_v = (int*)     alloc((size_t)(TOTE + 64)*4);            //  24.4 MB
  unsigned* bstage = (unsigned*)alloc((size_t)NBKT*BCAP*4);              //  32 MB
  int*      bcur   = (int*)     alloc((size_t)NBKT*4);
  int*      bbase  = (int*)     alloc((size_t)NBKT*4);

  // Xc aggregation panel: adaptive, capped so agg->GEMM handoff is L3-resident.
  size_t tile_bytes = (size_t)128*(14*128)*2;   // 448 KiB per 128-row tile
  size_t avail = (ws_size > off + 65536) ? (ws_size - off - 65536) : 0;
  int chunk_tiles = (int)(avail / tile_bytes);
  if (chunk_tiles > 256) chunk_tiles = 256;     // 112 MB
  if (chunk_tiles < 8) chunk_tiles = 8;
  unsigned* Xc = (unsigned*)alloc((size_t)chunk_tiles * tile_bytes);
  int nchunk = (TILES_TOTAL + chunk_tiles - 1) / chunk_tiles;
  (void)in_sizes; (void)n_in; (void)out_size;

  // ---- CSR build (two-pass binning; edges iteration-invariant) ----
  hipMemsetAsync(bcur, 0, (size_t)NBKT*4, stream);
  k_bucket<<<NBLK_BUCKET, 1024, 0, stream>>>(pre_u, pre_v, suc_u, suc_v,
                                             left_u, left_v, right_u, right_v,
                                             bcur, bstage);
  k_bscan<<<1, 256, 0, stream>>>(bcur, bbase, rowptr);
  k_place<<<NBKT, 256, 0, stream>>>(bstage, bcur, bbase, rowptr, edge_v);

  k_f2bf<<<NN*64/256, 256, 0, stream>>>(feat_in, featbf);

  for (int it = 0; it < NITER; it++) {
    k_bw<<<1024, 256, 0, stream>>>(W_ctr, W_pre, W_suc, W_left, W_right, W_ctr2, it, wcat, wc2);
    for (int c = 0; c < nchunk; c++) {
      int tile0 = c*chunk_tiles;
      int tiles = (TILES_TOTAL - tile0 < chunk_tiles) ? (TILES_TOTAL - tile0) : chunk_tiles;
      int base  = tile0*128;
      k_agg<<<tiles*32, 256, 0, stream>>>(featbf, rowptr, edge_v, Xc, base);
      gemm_big<<<tiles, 256, 0, stream>>>((const u16*)Xc, (const u16*)featbf, wcat,
                                          hbf, gn1w + it*DD, gn1b + it*DD, base);
    }
    gemm_sm<<<TILES_TOTAL, 256, 0, stream>>>((const u16*)hbf, wc2,
        (it == 0 ? feat_in : feat32),
        (it == NITER-1 ? (float*)d_out : feat32), featbf,
        gn2w + it*DD, gn2b + it*DD);
  }
}

// Round 6
// 4764.711 us; speedup vs baseline: 1.5032x; 1.0367x over previous
//
#include <hip/hip_runtime.h>

// Net_32323923870241: graph fusion block, MI355X (gfx950)
// Round 6: single fused GEMM kernel per chunk (GEMM1 + GN1/ReLU + GEMM2 +
// GN2/residual/ReLU), LDS XOR-swizzle on all MFMA fragment reads,
// bf16 ping-pong feature buffers (no fp32 residual stream, no hbf).

#define NN 250000
#define DD 128
#define EE 500000
#define ELE 50000
#define NITER 4
#define NL 14
#define M14 (NL*NN)              // 3,500,000
#define TOTE (12*EE + 2*ELE)     // 6,100,000 edges
#define KBIG (15*DD)             // 1920
#define BK 64
#define TILES_TOTAL ((NN + 127)/128)      // 1954
#define NBKT TILES_TOTAL
#define BCAP 4096
#define LK (128*NL)              // 1792 local keys per bucket
#define NBLK_BUCKET 256
#define EPB ((TOTE + NBLK_BUCKET - 1)/NBLK_BUCKET)   // 23829

typedef unsigned short u16;
typedef __attribute__((ext_vector_type(4))) float f32x4;
typedef __attribute__((ext_vector_type(8))) __bf16 bf16x8;

static __device__ __forceinline__ unsigned f2bf(float f) {
  unsigned u = __float_as_uint(f);
  return (u + 0x7fffu + ((u >> 16) & 1u)) >> 16;   // RNE
}
static __device__ __forceinline__ float bflo(unsigned w){ return __uint_as_float(w << 16); }
static __device__ __forceinline__ float bfhi(unsigned w){ return __uint_as_float(w & 0xffff0000u); }

static __device__ __forceinline__ void gload16(const u16* g, u16* l) {
  __builtin_amdgcn_global_load_lds(
      (const __attribute__((address_space(1))) void*)g,
      (__attribute__((address_space(3))) void*)l, 16, 0, 0);
}

static __device__ __forceinline__ int edge_u(int idx,
    const int* __restrict__ pu, const int* __restrict__ su,
    const int* __restrict__ lu, const int* __restrict__ ru) {
  if (idx < 12*EE) {
    int l = idx / EE; int e = idx - l*EE;
    return (l < 6) ? pu[l*EE + e] : su[(l-6)*EE + e];
  }
  int r = idx - 12*EE;
  return (r < ELE) ? lu[r] : ru[r - ELE];
}

static __device__ __forceinline__ void edge_luv(int idx,
    const int* __restrict__ pu, const int* __restrict__ pv,
    const int* __restrict__ su, const int* __restrict__ sv,
    const int* __restrict__ lu, const int* __restrict__ lv,
    const int* __restrict__ ru, const int* __restrict__ rv,
    int& l, int& u, int& v) {
  if (idx < 12*EE) {
    l = idx / EE; int e = idx - l*EE;
    if (l < 6) { u = pu[l*EE+e]; v = pv[l*EE+e]; }
    else       { u = su[(l-6)*EE+e]; v = sv[(l-6)*EE+e]; }
  } else {
    int r = idx - 12*EE;
    if (r < ELE) { l = 12; u = lu[r]; v = lv[r]; }
    else         { l = 13; u = ru[r-ELE]; v = rv[r-ELE]; }
  }
}

// ---------------- CSR build: two-pass LDS-histogram binning ----------------
__global__ __launch_bounds__(1024) void k_bucket(
    const int* __restrict__ pu, const int* __restrict__ pv,
    const int* __restrict__ su, const int* __restrict__ sv,
    const int* __restrict__ lu, const int* __restrict__ lv,
    const int* __restrict__ ru, const int* __restrict__ rv,
    int* __restrict__ bcur, unsigned* __restrict__ bstage) {
  __shared__ int cnt[NBKT];
  __shared__ int cur[NBKT];
  int t = threadIdx.x;
  for (int i=t; i<NBKT; i+=1024) cnt[i] = 0;
  __syncthreads();
  int e0 = blockIdx.x * EPB;
  int e1 = e0 + EPB; if (e1 > TOTE) e1 = TOTE;
  for (int idx = e0 + t; idx < e1; idx += 1024) {
    int u = edge_u(idx, pu, su, lu, ru);
    atomicAdd(&cnt[u >> 7], 1);
  }
  __syncthreads();
  for (int i=t; i<NBKT; i+=1024) {
    int c = cnt[i];
    cur[i] = c ? atomicAdd(&bcur[i], c) : 0;
  }
  __syncthreads();
  for (int idx = e0 + t; idx < e1; idx += 1024) {
    int l, u, v;
    edge_luv(idx, pu, pv, su, sv, lu, lv, ru, rv, l, u, v);
    int b = u >> 7;
    unsigned rec = ((unsigned)((u & 127)*NL + l) << 18) | (unsigned)v;
    int pos = atomicAdd(&cur[b], 1);
    if (pos < BCAP) bstage[(size_t)b*BCAP + pos] = rec;
  }
}

__global__ void k_bscan(const int* __restrict__ bcur, int* __restrict__ bbase,
                        int* __restrict__ rowptr) {
  __shared__ int wsum[4];
  int t = threadIdx.x, lane = t & 63, w = t >> 6;
  int v[8]; int s = 0;
  #pragma unroll
  for (int j=0;j<8;j++){
    int idx = t*8 + j;
    int x = 0;
    if (idx < NBKT) { x = bcur[idx]; if (x > BCAP) x = BCAP; }
    v[j] = s; s += x;
  }
  int ps = s;
  for (int d=1; d<64; d<<=1) { int o = __shfl_up(ps, d); if (lane >= d) ps += o; }
  if (lane == 63) wsum[w] = ps;
  __syncthreads();
  int woff = 0;
  for (int j=0;j<w;j++) woff += wsum[j];
  int excl = woff + ps - s;
  #pragma unroll
  for (int j=0;j<8;j++){
    int idx = t*8 + j;
    if (idx < NBKT) bbase[idx] = excl + v[j];
  }
  if (t == 255) rowptr[M14] = excl + s;
}

__global__ __launch_bounds__(256) void k_place(const unsigned* __restrict__ bstage,
    const int* __restrict__ bcur, const int* __restrict__ bbase,
    int* __restrict__ rowptr, int* __restrict__ edge_v) {
  __shared__ int lh[LK];
  __shared__ int lex[LK];
  __shared__ int wsum[4];
  int b = blockIdx.x, t = threadIdx.x;
  int lane = t & 63, w = t >> 6;
  int cnt = bcur[b]; if (cnt > BCAP) cnt = BCAP;
  int base = bbase[b];
  const unsigned* rec = bstage + (size_t)b*BCAP;
  for (int i=t; i<LK; i+=256) lh[i] = 0;
  __syncthreads();
  for (int e=t; e<cnt; e+=256) atomicAdd(&lh[rec[e]>>18], 1);
  __syncthreads();
  int s = 0;
  int my[7];
  #pragma unroll
  for (int j=0;j<7;j++){ my[j] = s; s += lh[t*7+j]; }
  int ps = s;
  for (int d=1; d<64; d<<=1) { int o = __shfl_up(ps, d); if (lane >= d) ps += o; }
  if (lane == 63) wsum[w] = ps;
  __syncthreads();
  int woff = 0;
  for (int j=0;j<w;j++) woff += wsum[j];
  int excl = woff + ps - s;
  #pragma unroll
  for (int j=0;j<7;j++) lex[t*7+j] = excl + my[j];
  __syncthreads();
  for (int i=t; i<LK; i+=256) rowptr[(size_t)b*LK + i] = base + lex[i];
  for (int i=t; i<LK; i+=256) lh[i] = lex[i];
  __syncthreads();
  for (int e=t; e<cnt; e+=256) {
    unsigned r = rec[e];
    int pos = atomicAdd(&lh[r>>18], 1);
    edge_v[base + pos] = (int)(r & 0x3FFFFu);
  }
}

// ---------------- per-iteration kernels ----------------
__global__ void k_f2bf(const float* __restrict__ in, unsigned* __restrict__ out) {
  int i = blockIdx.x*256 + threadIdx.x;
  float2 v = ((const float2*)in)[i];
  out[i] = f2bf(v.x) | (f2bf(v.y) << 16);
}

__global__ void k_bw(const float* __restrict__ Wc, const float* __restrict__ Wp,
                     const float* __restrict__ Ws, const float* __restrict__ Wl,
                     const float* __restrict__ Wr, const float* __restrict__ Wc2,
                     int it, u16* __restrict__ wcat, u16* __restrict__ wc2) {
  int i = blockIdx.x*256 + threadIdx.x;
  if (i < 128*KBIG) {
    int r = i / KBIG, K = i - r*KBIG;
    int s = K >> 7, c = K & 127;
    float val;
    if (s == 0)       val = Wc[(it*128 + r)*128 + c];
    else if (s <= 6)  val = Wp[((it*6 + (s-1))*128 + r)*128 + c];
    else if (s <= 12) val = Ws[((it*6 + (s-7))*128 + r)*128 + c];
    else if (s == 13) val = Wl[(it*128 + r)*128 + c];
    else              val = Wr[(it*128 + r)*128 + c];
    wcat[i] = (u16)f2bf(val);
  } else {
    int j = i - 128*KBIG;
    wc2[j] = (u16)f2bf(Wc2[it*16384 + j]);
  }
}

// wave-per-node aggregation over 14 CSR lists
__global__ __launch_bounds__(256) void k_agg(const unsigned* __restrict__ featbf,
    const int* __restrict__ rowptr, const int* __restrict__ edge_v,
    unsigned* __restrict__ X, int chunk_base) {
  int wid = threadIdx.x >> 6, lane = threadIdx.x & 63;
  int nl = blockIdx.x*4 + wid;
  int node = chunk_base + nl;
  size_t xb = (size_t)nl * (14*64);
  if (node >= NN) {
    #pragma unroll
    for (int s=0;s<14;s++) X[xb + s*64 + lane] = 0;
    return;
  }
  int rp = 0;
  if (lane < 15) rp = rowptr[node*NL + lane];
  int st0 = __shfl(rp, 0);
  int cnt = __shfl(rp, 14) - st0;
  float ax = 0.f, ay = 0.f;
  int s = 0;
  int nextb = __shfl(rp, 1);
  int vv = 0;
  for (int base = 0; base < cnt; base += 8) {
    if ((base & 63) == 0) vv = edge_v[st0 + base + lane];
    unsigned wrow[8];
    int m = cnt - base; if (m > 8) m = 8;
    #pragma unroll
    for (int q=0;q<8;q++)
      if (q < m) {
        int v = __shfl(vv, (base & 63) + q);
        wrow[q] = featbf[(size_t)v*64 + lane];
      }
    for (int q=0;q<m;q++) {
      int e = st0 + base + q;
      while (e == nextb && s < 14) {
        X[xb + s*64 + lane] = f2bf(ax) | (f2bf(ay) << 16);
        ax = 0.f; ay = 0.f; s++;
        int ni = s + 1; if (ni > 14) ni = 14;
        nextb = __shfl(rp, ni);
      }
      ax += bflo(wrow[q]); ay += bfhi(wrow[q]);
    }
  }
  while (s < 14) {
    X[xb + s*64 + lane] = f2bf(ax) | (f2bf(ay) << 16);
    ax = 0.f; ay = 0.f; s++;
  }
}

// Fully fused per-128-row-tile pipeline:
//   acc = [fbf | Xc] @ wcat^T          (K=1920, swizzled LDS staging)
//   h   = relu(GN1(acc))  -> LDS bf16  (stats via shfl + 2KB LDS)
//   a2  = h @ wc2^T                    (wc2 frags read from global/L2)
//   out = relu(GN2(a2) + res_bf16)     -> fout (+ out32 on last iter)
__global__ __launch_bounds__(256) void gemm_fused(
    const u16* __restrict__ Xc, const u16* __restrict__ fbf,
    const u16* __restrict__ Bw, const u16* __restrict__ wc2g,
    unsigned* __restrict__ fout, float* __restrict__ out32, int last,
    const float* __restrict__ g1w, const float* __restrict__ g1b,
    const float* __restrict__ g2w, const float* __restrict__ g2b,
    int row0_abs) {
  __shared__ u16 smem[2*128*BK];        // As/Bs in K-loop; h[128][128] after
  __shared__ float stats[2][128][2];    // [wn][row][{sum,sumsq}]
  u16* As = smem; u16* Bs = smem + 128*BK;
  int tid = threadIdx.x, wid = tid >> 6, lane = tid & 63;
  int wm = wid >> 1, wn = wid & 1;
  int g = lane >> 4, l15 = lane & 15, l7 = lane & 7;
  int tile_row = blockIdx.x * 128;
  f32x4 acc[4][4] = {};
  int srow8 = lane >> 3;
  int scol = ((lane & 7) ^ srow8) * 8;        // pre-swizzled source col (u16)
  for (int k0 = 0; k0 < KBIG; k0 += BK) {
    __syncthreads();
    if (k0 < DD) {
      #pragma unroll
      for (int j=0;j<4;j++) {
        int seg = wid + j*4; int r = seg*8 + srow8;
        int arow = row0_abs + tile_row + r; if (arow > NN-1) arow = NN-1;
        gload16(fbf + (size_t)arow*DD + (k0 + scol), &As[seg*512]);
        gload16(Bw + (size_t)r*KBIG + (k0 + scol), &Bs[seg*512]);
      }
    } else {
      #pragma unroll
      for (int j=0;j<4;j++) {
        int seg = wid + j*4; int r = seg*8 + srow8;
        gload16(Xc + (size_t)(tile_row + r)*(14*128) + (k0 - DD + scol), &As[seg*512]);
        gload16(Bw + (size_t)r*KBIG + (k0 + scol), &Bs[seg*512]);
      }
    }
    __syncthreads();
    #pragma unroll
    for (int kk=0; kk<2; kk++) {
      bf16x8 af[4], bfr[4];
      #pragma unroll
      for (int mt=0; mt<4; mt++)
        af[mt] = *(const bf16x8*)&As[((wm*64 + mt*16 + l15)*BK + kk*32 + g*8) ^ (l7<<3)];
      #pragma unroll
      for (int nt=0; nt<4; nt++)
        bfr[nt] = *(const bf16x8*)&Bs[((wn*64 + nt*16 + l15)*BK + kk*32 + g*8) ^ (l7<<3)];
      #pragma unroll
      for (int mt=0; mt<4; mt++)
        #pragma unroll
        for (int nt=0; nt<4; nt++)
          acc[mt][nt] = __builtin_amdgcn_mfma_f32_16x16x32_bf16(af[mt], bfr[nt], acc[mt][nt], 0, 0, 0);
    }
  }
  __syncthreads();                      // As/Bs free -> becomes h

  // ---- GN1 stats: per-row sum/sumsq (butterfly over 16-lane group, cross-wn via LDS)
  #pragma unroll
  for (int mt=0; mt<4; mt++)
    #pragma unroll
    for (int r=0; r<4; r++) {
      float s = 0.f, q = 0.f;
      #pragma unroll
      for (int nt=0; nt<4; nt++) { float v = acc[mt][nt][r]; s += v; q += v*v; }
      #pragma unroll
      for (int d=1; d<16; d<<=1) { s += __shfl_xor(s, d); q += __shfl_xor(q, d); }
      if (l15 == 0) {
        int R = wm*64 + mt*16 + g*4 + r;
        stats[wn][R][0] = s; stats[wn][R][1] = q;
      }
    }
  __syncthreads();

  // ---- h = relu(GN1(acc)) -> LDS bf16 (swizzled), pair-packed u32 writes
  float w1[4], b1[4], w2[4], b2[4];
  #pragma unroll
  for (int nt=0; nt<4; nt++) {
    int C = wn*64 + nt*16 + l15;
    w1[nt] = g1w[C]; b1[nt] = g1b[C];
    w2[nt] = g2w[C]; b2[nt] = g2b[C];
  }
  #pragma unroll
  for (int mt=0; mt<4; mt++)
    #pragma unroll
    for (int r=0; r<4; r++) {
      int R = wm*64 + mt*16 + g*4 + r;
      float ts = stats[0][R][0] + stats[1][R][0];
      float tq = stats[0][R][1] + stats[1][R][1];
      float mu = ts*(1.f/DD), var = tq*(1.f/DD) - mu*mu;
      float rs = rsqrtf(var + 1e-5f);
      #pragma unroll
      for (int nt=0; nt<4; nt++) {
        int C = wn*64 + nt*16 + l15;
        float y = fmaxf(fmaf((acc[mt][nt][r]-mu)*rs, w1[nt], b1[nt]), 0.f);
        float p = __shfl_xor(y, 1);
        if (!(lane & 1)) {
          unsigned word = f2bf(y) | (f2bf(p) << 16);
          int idx = (R*128 + (C & ~1)) ^ ((R&7)<<3);
          *(unsigned*)&smem[idx] = word;
        }
      }
    }
  __syncthreads();                      // h ready

  // ---- GEMM2: a2 = h @ wc2^T (B-frags from global, A-frags from swizzled LDS)
  f32x4 a2[4][4] = {};
  #pragma unroll
  for (int kk2=0; kk2<4; kk2++) {
    bf16x8 wf[4], hf[4];
    #pragma unroll
    for (int nt=0; nt<4; nt++)
      wf[nt] = *(const bf16x8*)&wc2g[(size_t)(wn*64 + nt*16 + l15)*DD + kk2*32 + g*8];
    #pragma unroll
    for (int mt=0; mt<4; mt++)
      hf[mt] = *(const bf16x8*)&smem[((wm*64 + mt*16 + l15)*DD + kk2*32 + g*8) ^ (l7<<3)];
    #pragma unroll
    for (int mt=0; mt<4; mt++)
      #pragma unroll
      for (int nt=0; nt<4; nt++)
        a2[mt][nt] = __builtin_amdgcn_mfma_f32_16x16x32_bf16(hf[mt], wf[nt], a2[mt][nt], 0, 0, 0);
  }
  __syncthreads();                      // protect stats reuse

  // ---- GN2 stats
  #pragma unroll
  for (int mt=0; mt<4; mt++)
    #pragma unroll
    for (int r=0; r<4; r++) {
      float s = 0.f, q = 0.f;
      #pragma unroll
      for (int nt=0; nt<4; nt++) { float v = a2[mt][nt][r]; s += v; q += v*v; }
      #pragma unroll
      for (int d=1; d<16; d<<=1) { s += __shfl_xor(s, d); q += __shfl_xor(q, d); }
      if (l15 == 0) {
        int R = wm*64 + mt*16 + g*4 + r;
        stats[wn][R][0] = s; stats[wn][R][1] = q;
      }
    }
  __syncthreads();

  // ---- final: relu(GN2 + res), write fout (+ out32 last iter)
  #pragma unroll
  for (int mt=0; mt<4; mt++)
    #pragma unroll
    for (int r=0; r<4; r++) {
      int R = wm*64 + mt*16 + g*4 + r;
      int grow = row0_abs + tile_row + R;
      float ts = stats[0][R][0] + stats[1][R][0];
      float tq = stats[0][R][1] + stats[1][R][1];
      float mu = ts*(1.f/DD), var = tq*(1.f/DD) - mu*mu;
      float rs = rsqrtf(var + 1e-5f);
      bool ok = grow < NN;
      #pragma unroll
      for (int nt=0; nt<4; nt++) {
        int C = wn*64 + nt*16 + l15;
        float yv = fmaf((a2[mt][nt][r]-mu)*rs, w2[nt], b2[nt]);
        unsigned rw = ok ? ((const unsigned*)fbf)[(size_t)grow*64 + (C>>1)] : 0u;
        float resv = (lane & 1) ? bfhi(rw) : bflo(rw);
        float o = fmaxf(yv + resv, 0.f);
        if (last && ok) out32[(size_t)grow*DD + C] = o;
        float p = __shfl_xor(o, 1);
        if (!(lane & 1) && ok)
          fout[(size_t)grow*64 + (C>>1)] = f2bf(o) | (f2bf(p) << 16);
      }
    }
}

extern "C" void kernel_launch(void* const* d_in, const int* in_sizes, int n_in,
                              void* d_out, int out_size, void* d_ws, size_t ws_size,
                              hipStream_t stream) {
  const float* feat_in = (const float*)d_in[0];
  const int* pre_u  = (const int*)d_in[1];
  const int* pre_v  = (const int*)d_in[2];
  const int* suc_u  = (const int*)d_in[3];
  const int* suc_v  = (const int*)d_in[4];
  const int* left_u = (const int*)d_in[5];
  const int* left_v = (const int*)d_in[6];
  const int* right_u= (const int*)d_in[7];
  const int* right_v= (const int*)d_in[8];
  const float* W_ctr  = (const float*)d_in[9];
  const float* W_pre  = (const float*)d_in[10];
  const float* W_suc  = (const float*)d_in[11];
  const float* W_left = (const float*)d_in[12];
  const float* W_right= (const float*)d_in[13];
  const float* gn1w   = (const float*)d_in[14];
  const float* gn1b   = (const float*)d_in[15];
  const float* W_ctr2 = (const float*)d_in[16];
  const float* gn2w   = (const float*)d_in[17];
  const float* gn2b   = (const float*)d_in[18];

  char* ws = (char*)d_ws;
  size_t off = 0;
  auto alloc = [&](size_t bytes) -> char* {
    char* p = ws + off; off += (bytes + 255) & ~(size_t)255; return p;
  };
  unsigned* featA  = (unsigned*)alloc((size_t)NN*64*4);                  // 64 MB
  unsigned* featB  = (unsigned*)alloc((size_t)NN*64*4);                  // 64 MB
  u16*      wcat   = (u16*)     alloc((size_t)128*KBIG*2);
  u16*      wc2    = (u16*)     alloc((size_t)128*128*2);
  int*      rowptr = (int*)     alloc(((size_t)NBKT*LK + 1)*4);          // 14 MB
  int*      edge_v = (int*)     alloc((size_t)(TOTE + 64)*4);            // 24.4 MB
  unsigned* bstage = (unsigned*)alloc((size_t)NBKT*BCAP*4);              // 32 MB
  int*      bcur   = (int*)     alloc((size_t)NBKT*4);
  int*      bbase  = (int*)     alloc((size_t)NBKT*4);

  size_t tile_bytes = (size_t)128*(14*128)*2;   // 448 KiB per 128-row tile
  size_t avail = (ws_size > off + 65536) ? (ws_size - off - 65536) : 0;
  int chunk_tiles = (int)(avail / tile_bytes);
  if (chunk_tiles > 256) chunk_tiles = 256;     // 112 MB, L3-friendly handoff
  if (chunk_tiles < 8) chunk_tiles = 8;
  unsigned* Xc = (unsigned*)alloc((size_t)chunk_tiles * tile_bytes);
  int nchunk = (TILES_TOTAL + chunk_tiles - 1) / chunk_tiles;
  (void)in_sizes; (void)n_in; (void)out_size;

  // ---- CSR build (edges iteration-invariant) ----
  hipMemsetAsync(bcur, 0, (size_t)NBKT*4, stream);
  k_bucket<<<NBLK_BUCKET, 1024, 0, stream>>>(pre_u, pre_v, suc_u, suc_v,
                                             left_u, left_v, right_u, right_v,
                                             bcur, bstage);
  k_bscan<<<1, 256, 0, stream>>>(bcur, bbase, rowptr);
  k_place<<<NBKT, 256, 0, stream>>>(bstage, bcur, bbase, rowptr, edge_v);

  k_f2bf<<<NN*64/256, 256, 0, stream>>>(feat_in, featA);

  for (int it = 0; it < NITER; it++) {
    unsigned* fin  = (it & 1) ? featB : featA;
    unsigned* fo   = (it & 1) ? featA : featB;
    int last = (it == NITER-1) ? 1 : 0;
    k_bw<<<1024, 256, 0, stream>>>(W_ctr, W_pre, W_suc, W_left, W_right, W_ctr2, it, wcat, wc2);
    for (int c = 0; c < nchunk; c++) {
      int tile0 = c*chunk_tiles;
      int tiles = (TILES_TOTAL - tile0 < chunk_tiles) ? (TILES_TOTAL - tile0) : chunk_tiles;
      int base  = tile0*128;
      k_agg<<<tiles*32, 256, 0, stream>>>(fin, rowptr, edge_v, Xc, base);
      gemm_fused<<<tiles, 256, 0, stream>>>((const u16*)Xc, (const u16*)fin, wcat, wc2,
                                            fo, (float*)d_out, last,
                                            gn1w + it*DD, gn1b + it*DD,
                                            gn2w + it*DD, gn2b + it*DD, base);
    }
  }
}